// Round 11
// baseline (2349.433 us; speedup 1.0000x reference)
//
#include <hip/hip_runtime.h>
#include <math.h>

// ---------------- static config ----------------
#define NF 32
#define NPATHS 34

typedef __attribute__((ext_vector_type(8))) short bf16x8;
typedef __attribute__((ext_vector_type(4))) float f32x4;

__device__ __forceinline__ unsigned short f2bf(float v){
  unsigned u = __float_as_uint(v);
  u += 0x7fffu + ((u>>16)&1u);
  return (unsigned short)(u>>16);
}
__device__ __forceinline__ float bf2f(unsigned short h){
  return __uint_as_float(((unsigned)h)<<16);
}

struct PathTab { int l1[NPATHS]; int l2[NPATHS]; int l3[NPATHS]; };
constexpr PathTab mkpaths(){
  PathTab t{}; int n=0;
  for(int a=0;a<=3;a++)for(int b=0;b<=3;b++)for(int c=0;c<=3;c++){
    int lo = a>b ? a-b : b-a;
    if(c>=lo && c<=a+b){ t.l1[n]=a; t.l2[n]=b; t.l3[n]=c; n++; }
  }
  return t;
}
constexpr PathTab PT = mkpaths();

// ---------------- compile-time Wigner-3j (exact replica of reference math) ----------------
struct FactT { double v[22]; };
constexpr FactT mkfactT(){ FactT f{}; f.v[0]=1.0; for(int i=1;i<22;i++) f.v[i]=f.v[i-1]*(double)i; return f; }
constexpr FactT FT = mkfactT();
constexpr double cfact(int n){ return FT.v[n]; }

constexpr double csqrt(double x){
  if(x<=0.0) return 0.0;
  double g = x<1.0 ? 1.0 : x;
  for(int i=0;i<40;i++) g=0.5*(g+x/g);
  return g;
}

constexpr double su2cg(int j1,int j2,int j3,int m1,int m2){
  int m3=m1+m2;
  if(m3<-j3||m3>j3) return 0.0;
  double pref = (double)(2*j3+1)*cfact(j3+j1-j2)*cfact(j3-j1+j2)*cfact(j1+j2-j3)/cfact(j1+j2+j3+1);
  pref *= cfact(j3+m3)*cfact(j3-m3)*cfact(j1-m1)*cfact(j1+m1)*cfact(j2-m2)*cfact(j2+m2);
  pref = csqrt(pref);
  int k0=0; if(j2-j3-m1>k0)k0=j2-j3-m1; if(j1-j3+m2>k0)k0=j1-j3+m2;
  int k1=j1+j2-j3; if(j1-m1<k1)k1=j1-m1; if(j2+m2<k1)k1=j2+m2;
  double s=0.0;
  for(int k=k0;k<=k1;k++){
    double d = cfact(k)*cfact(j1+j2-j3-k)*cfact(j1-m1-k)*cfact(j2+m2-k)*cfact(j3-j2+m1+k)*cfact(j3-j1-m2+k);
    s += (k&1)? -1.0/d : 1.0/d;
  }
  return pref*s;
}

struct ccd { double x, y; };
constexpr ccd cqval(int l,int r,int col){
  const double is2 = 0.70710678118654752440;
  double re=0.0, im=0.0;
  if (r<l){ if (col==2*l-r) re=is2; else if (col==r) im=-is2; }
  else if (r==l){ if (col==l) re=1.0; }
  else { double s = ((r-l)&1)? -1.0:1.0;
         if (col==r) re=s*is2; else if (col==2*l-r) im=s*is2; }
  ccd v{re,im};
  switch(l&3){           // multiply by (-i)^l
    case 1: return ccd{ v.y, -v.x };
    case 2: return ccd{-v.x, -v.y };
    case 3: return ccd{-v.y,  v.x };
    default: return v;
  }
}

constexpr double w3entry(int l1,int l2,int l3,int i,int j,int k){
  double re=0.0;
  for(int a=0;a<2*l1+1;a++){
    ccd qa=cqval(l1,a,i); if(qa.x==0.0&&qa.y==0.0) continue;
    for(int b=0;b<2*l2+1;b++){
      ccd qb=cqval(l2,b,j); if(qb.x==0.0&&qb.y==0.0) continue;
      int m1=a-l1, m2=b-l2, m3=m1+m2;
      if(m3<-l3||m3>l3) continue;
      int c=m3+l3;
      double cg=su2cg(l1,l2,l3,m1,m2); if(cg==0.0) continue;
      ccd qc=cqval(l3,c,k); qc.y=-qc.y;   // conj
      if(qc.x==0.0&&qc.y==0.0) continue;
      ccd ab{qa.x*qb.x-qa.y*qb.y, qa.x*qb.y+qa.y*qb.x};
      re += cg*(ab.x*qc.x - ab.y*qc.y);
    }
  }
  return re;
}

template<int L1,int L2,int L3> struct W3Arr { float v[(2*L1+1)*(2*L2+1)*(2*L3+1)]; };
template<int L1,int L2,int L3> constexpr W3Arr<L1,L2,L3> mkW3(double scale){
  W3Arr<L1,L2,L3> r{};
  for(int i=0;i<2*L1+1;i++)
    for(int j=0;j<2*L2+1;j++)
      for(int k=0;k<2*L3+1;k++)
        r.v[(i*(2*L2+1)+j)*(2*L3+1)+k] = (float)(w3entry(L1,L2,L3,i,j,k)*scale);
  return r;
}
template<int L1,int L2,int L3> constexpr W3Arr<L1,L2,L3> W3V = mkW3<L1,L2,L3>(1.0);
template<int L1,int L2,int L3> constexpr W3Arr<L1,L2,L3> W3N = mkW3<L1,L2,L3>(1.0/csqrt(2.0*L3+1.0));

// SH recursion scales (replica of reference _sh_scales, float64 like numpy)
struct SCt { double sc2, sc3; };
constexpr SCt mksc(){
  double v0=0.2,v1=-0.6,v2=0.7;
  double nv=csqrt(v0*v0+v1*v1+v2*v2);
  double s3=csqrt(3.0);
  double y1[3]={s3*v0/nv, s3*v1/nv, s3*v2/nv};
  double t2[5]={0,0,0,0,0}; double n2=0.0;
  for(int c=0;c<5;c++){
    double s=0.0;
    for(int a=0;a<3;a++)for(int b=0;b<3;b++) s += w3entry(1,1,2,a,b,c)*y1[a]*y1[b];
    t2[c]=s; n2+=s*s;
  }
  double sc2=csqrt(5.0)/csqrt(n2);
  double y2[5]={sc2*t2[0],sc2*t2[1],sc2*t2[2],sc2*t2[3],sc2*t2[4]};
  double n3=0.0;
  for(int c=0;c<7;c++){
    double s=0.0;
    for(int a=0;a<5;a++)for(int b=0;b<3;b++) s += w3entry(2,1,3,a,b,c)*y2[a]*y1[b];
    n3+=s*s;
  }
  double sc3=csqrt(7.0)/csqrt(n3);
  return SCt{sc2,sc3};
}
constexpr SCt SCV = mksc();

// ---------------- template-unrolled TP with literal W3J, true-zero elision ----------------
template<bool NORM,int l1,int l2,int l3,int A,int B,int C>
__device__ __forceinline__ void w3term(const float* __restrict__ x, const float* __restrict__ y,
                                       float rv, float* __restrict__ acc){
  constexpr float w = NORM ? W3N<l1,l2,l3>.v[(A*(2*l2+1)+B)*(2*l3+1)+C]
                           : W3V<l1,l2,l3>.v[(A*(2*l2+1)+B)*(2*l3+1)+C];
  if constexpr (w!=0.0f)
    acc[l3*l3+C] = fmaf(w, x[l1*l1+A]*y[l2*l2+B]*rv, acc[l3*l3+C]);
}
template<bool NORM,int l1,int l2,int l3,int A,int B,int C>
__device__ __forceinline__ void w3loopC(const float* x,const float* y,float rv,float* acc){
  if constexpr (C<2*l3+1){
    w3term<NORM,l1,l2,l3,A,B,C>(x,y,rv,acc);
    w3loopC<NORM,l1,l2,l3,A,B,C+1>(x,y,rv,acc);
  }
}
template<bool NORM,int l1,int l2,int l3,int A,int B>
__device__ __forceinline__ void w3loopB(const float* x,const float* y,float rv,float* acc){
  if constexpr (B<2*l2+1){
    w3loopC<NORM,l1,l2,l3,A,B,0>(x,y,rv,acc);
    w3loopB<NORM,l1,l2,l3,A,B+1>(x,y,rv,acc);
  }
}
template<bool NORM,int l1,int l2,int l3,int A>
__device__ __forceinline__ void w3loopA(const float* x,const float* y,float rv,float* acc){
  if constexpr (A<2*l1+1){
    w3loopB<NORM,l1,l2,l3,A,0>(x,y,rv,acc);
    w3loopA<NORM,l1,l2,l3,A+1>(x,y,rv,acc);
  }
}

// rr = 5 bf16x8 vectors holding path weights f-major; extraction is constexpr-indexed
template<bool L0,int P>
__device__ __forceinline__ void tp_paths(const float* hs,const float* yv,
                                         const bf16x8* rr, float* acc){
  if constexpr (P<NPATHS){
    constexpr int l1=PT.l1[P], l2=PT.l2[P], l3=PT.l3[P];
    if constexpr (!(L0 && l1!=0)){
      float rv = bf2f((unsigned short)rr[P>>3][P&7]);
      w3loopA<false,l1,l2,l3,0>(hs,yv,rv,acc);
    }
    tp_paths<L0,P+1>(hs,yv,rr,acc);
  }
}

template<int P>
__device__ __forceinline__ void tpn_paths(const float* x,const float* y,float* o){
  if constexpr (P<NPATHS){
    constexpr int l1=PT.l1[P], l2=PT.l2[P], l3=PT.l3[P];
    w3loopA<true,l1,l2,l3,0>(x,y,1.0f,o);
    tpn_paths<P+1>(x,y,o);
  }
}

// ---------------- CSR build: degree count, scan, fill ----------------
__global__ __launch_bounds__(256) void k_count(
    const int* __restrict__ rcv, int* __restrict__ deg, int E)
{
  int e=blockIdx.x*256+threadIdx.x;
  if(e>=E) return;
  atomicAdd(&deg[rcv[e]],1);
}

#define SCAN_PER 32
__global__ __launch_bounds__(1024) void k_scan(
    const int* __restrict__ deg, int* __restrict__ row,
    int* __restrict__ cur, int N)
{
  __shared__ int part[1024];
  int t=threadIdx.x;
  int per=(N+1023)/1024; if(per>SCAN_PER) per=SCAN_PER;
  int base=t*per;
  int loc[SCAN_PER];
  int s=0;
  for(int i=0;i<per;i++){ int idx=base+i; int v=(idx<N)? deg[idx]:0; loc[i]=s; s+=v; }
  part[t]=s;
  __syncthreads();
  for(int off=1;off<1024;off<<=1){
    int v=(t>=off)? part[t-off]:0;
    __syncthreads();
    part[t]+=v;
    __syncthreads();
  }
  int ex=(t==0)?0:part[t-1];
  for(int i=0;i<per;i++){
    int idx=base+i;
    if(idx<N){ int r=ex+loc[i]; row[idx]=r; cur[idx]=r; }
  }
  if(t==1023) row[N]=part[1023];
}

__global__ __launch_bounds__(256) void k_fill(
    const int* __restrict__ rcv, int* __restrict__ cur,
    int* __restrict__ eid, int E)
{
  int e=blockIdx.x*256+threadIdx.x;
  if(e>=E) return;
  int pos=atomicAdd(&cur[rcv[e]],1);
  eid[pos]=e;
}

// ---------------- per-edge geometry (receiver-sorted order): SH + radial basis ----------------
__global__ __launch_bounds__(256) void k_edge_setup(
    const float* __restrict__ vec, const int* __restrict__ snd,
    const int* __restrict__ eid, float* __restrict__ Y,
    float* __restrict__ rad, int* __restrict__ snd_s, int E)
{
  int j = blockIdx.x*256+threadIdx.x;
  if (j>=E) return;
  int e = eid[j];
  snd_s[j]=snd[e];
  float vx=vec[3*e], vy=vec[3*e+1], vz=vec[3*e+2];
  float r=sqrtf(vx*vx+vy*vy+vz*vz);
  float inv=1.0f/fmaxf(r,1e-9f);
  float y[16];
  y[0]=1.0f;
  const float s3=1.7320508075688772f;
  y[1]=s3*vx*inv; y[2]=s3*vy*inv; y[3]=s3*vz*inv;
  constexpr float sc2=(float)SCV.sc2, sc3=(float)SCV.sc3;
  {
    float t[16];
    #pragma unroll
    for(int c=0;c<16;c++) t[c]=0.f;
    w3loopA<false,1,1,2,0>(y,y,1.0f,t);     // t[4..8] = einsum(w112, y1, y1)
    #pragma unroll
    for(int c=0;c<5;c++) y[4+c]=sc2*t[4+c];
    w3loopA<false,2,1,3,0>(y,y,1.0f,t);     // t[9..15] = einsum(w213, y2, y1)
    #pragma unroll
    for(int c=0;c<7;c++) y[9+c]=sc3*t[9+c];
  }
  float4* Yp=(float4*)(Y+(size_t)j*16);
  Yp[0]=make_float4(y[0],y[1],y[2],y[3]);
  Yp[1]=make_float4(y[4],y[5],y[6],y[7]);
  Yp[2]=make_float4(y[8],y[9],y[10],y[11]);
  Yp[3]=make_float4(y[12],y[13],y[14],y[15]);
  float x = r*0.2f;
  float env=0.f;
  if (x<1.0f){
    float x2=x*x; float x4=x2*x2; float x5=x4*x;
    env = 1.0f - 21.0f*x5 + 35.0f*x5*x - 15.0f*x5*x2;
  }
  const float cb = 0.632455532033675866f; // sqrt(2/5)
  float base = inv*env*cb;
  #pragma unroll
  for(int n=1;n<=8;n++)
    rad[(size_t)j*8 + n-1] = base*sinf(3.14159265358979323846f * x * (float)n);
}

// ---------------- node init: scalar embedding ----------------
__global__ __launch_bounds__(256) void k_node_init(
    const float* __restrict__ embed, const int* __restrict__ z,
    float* __restrict__ feats, int N)
{
  int t = blockIdx.x*256+threadIdx.x;
  int n=t>>5, f=t&31;
  if(n>=N) return;
  float v = embed[z[n]*NF + f];
  float4* p=(float4*)(feats + (size_t)n*512 + f*16);
  p[0]=make_float4(v,0.f,0.f,0.f);
  p[1]=make_float4(0.f,0.f,0.f,0.f);
  p[2]=make_float4(0.f,0.f,0.f,0.f);
  p[3]=make_float4(0.f,0.f,0.f,0.f);
}

// ---------------- per-l channel-mixing linear (f32 out) ----------------
__global__ __launch_bounds__(256) void k_lin(
    const float* __restrict__ in, float* __restrict__ out,
    const float* __restrict__ w, const int* __restrict__ z, int zstride, int N)
{
  int t=blockIdx.x*256+threadIdx.x;
  int n=t>>5, g=t&31;
  if(n>=N) return;
  const float* wp = w + (z ? (size_t)z[n]*(size_t)zstride : 0);
  const float* ip = in + (size_t)n*512;
  float acc[16];
  #pragma unroll
  for(int c=0;c<16;c++) acc[c]=0.f;
  #pragma unroll 8
  for(int f=0; f<NF; f++){
    const float4* xp = (const float4*)(ip + f*16);
    float4 x0=xp[0], x1=xp[1], x2=xp[2], x3=xp[3];
    float w0v=wp[(f<<5)+g], w1v=wp[1024+(f<<5)+g], w2v=wp[2048+(f<<5)+g], w3v=wp[3072+(f<<5)+g];
    acc[0]  = fmaf(x0.x,w0v,acc[0]);
    acc[1]  = fmaf(x0.y,w1v,acc[1]);
    acc[2]  = fmaf(x0.z,w1v,acc[2]);
    acc[3]  = fmaf(x0.w,w1v,acc[3]);
    acc[4]  = fmaf(x1.x,w2v,acc[4]);
    acc[5]  = fmaf(x1.y,w2v,acc[5]);
    acc[6]  = fmaf(x1.z,w2v,acc[6]);
    acc[7]  = fmaf(x1.w,w2v,acc[7]);
    acc[8]  = fmaf(x2.x,w2v,acc[8]);
    acc[9]  = fmaf(x2.y,w3v,acc[9]);
    acc[10] = fmaf(x2.z,w3v,acc[10]);
    acc[11] = fmaf(x2.w,w3v,acc[11]);
    acc[12] = fmaf(x3.x,w3v,acc[12]);
    acc[13] = fmaf(x3.y,w3v,acc[13]);
    acc[14] = fmaf(x3.z,w3v,acc[14]);
    acc[15] = fmaf(x3.w,w3v,acc[15]);
  }
  float4* op=(float4*)(out + (size_t)n*512 + g*16);
  op[0]=make_float4(acc[0],acc[1],acc[2],acc[3]);
  op[1]=make_float4(acc[4],acc[5],acc[6],acc[7]);
  op[2]=make_float4(acc[8],acc[9],acc[10],acc[11]);
  op[3]=make_float4(acc[12],acc[13],acc[14],acc[15]);
}

// ---------------- per-l channel-mixing linear (bf16 out, for fused-TP input) ----------------
__global__ __launch_bounds__(256) void k_lin16(
    const float* __restrict__ in, unsigned short* __restrict__ out,
    const float* __restrict__ w, int N)
{
  int t=blockIdx.x*256+threadIdx.x;
  int n=t>>5, g=t&31;
  if(n>=N) return;
  const float* wp = w;
  const float* ip = in + (size_t)n*512;
  float acc[16];
  #pragma unroll
  for(int c=0;c<16;c++) acc[c]=0.f;
  #pragma unroll 8
  for(int f=0; f<NF; f++){
    const float4* xp = (const float4*)(ip + f*16);
    float4 x0=xp[0], x1=xp[1], x2=xp[2], x3=xp[3];
    float w0v=wp[(f<<5)+g], w1v=wp[1024+(f<<5)+g], w2v=wp[2048+(f<<5)+g], w3v=wp[3072+(f<<5)+g];
    acc[0]  = fmaf(x0.x,w0v,acc[0]);
    acc[1]  = fmaf(x0.y,w1v,acc[1]);
    acc[2]  = fmaf(x0.z,w1v,acc[2]);
    acc[3]  = fmaf(x0.w,w1v,acc[3]);
    acc[4]  = fmaf(x1.x,w2v,acc[4]);
    acc[5]  = fmaf(x1.y,w2v,acc[5]);
    acc[6]  = fmaf(x1.z,w2v,acc[6]);
    acc[7]  = fmaf(x1.w,w2v,acc[7]);
    acc[8]  = fmaf(x2.x,w2v,acc[8]);
    acc[9]  = fmaf(x2.y,w3v,acc[9]);
    acc[10] = fmaf(x2.z,w3v,acc[10]);
    acc[11] = fmaf(x2.w,w3v,acc[11]);
    acc[12] = fmaf(x3.x,w3v,acc[12]);
    acc[13] = fmaf(x3.y,w3v,acc[13]);
    acc[14] = fmaf(x3.z,w3v,acc[14]);
    acc[15] = fmaf(x3.w,w3v,acc[15]);
  }
  bf16x8 o0,o1;
  #pragma unroll
  for(int c=0;c<8;c++){ o0[c]=(short)f2bf(acc[c]); o1[c]=(short)f2bf(acc[8+c]); }
  bf16x8* op=(bf16x8*)(out + (size_t)n*512 + g*16);
  op[0]=o0; op[1]=o1;
}

// ---------------- radial MLP hidden layers (bf16 output) ----------------
__global__ __launch_bounds__(256) void k_radial(
    const float* __restrict__ rad, const float* __restrict__ w0,
    const float* __restrict__ w1, unsigned short* __restrict__ hid, int E)
{
  __shared__ float w0s[8*64];
  __shared__ float w1s[64*64];
  int tid=threadIdx.x;
  for(int i=tid;i<512;i+=256) w0s[i]=w0[i];
  for(int i=tid;i<4096;i+=256) w1s[i]=w1[i];
  __syncthreads();
  int e=blockIdx.x*256+tid;
  if(e>=E) return;
  const float4* rp=(const float4*)(rad+(size_t)e*8);
  float4 ra=rp[0], rb=rp[1];
  float rv[8]={ra.x,ra.y,ra.z,ra.w,rb.x,rb.y,rb.z,rb.w};
  float h1[64];
  #pragma unroll 8
  for(int j=0;j<64;j++){
    float a=0.f;
    #pragma unroll
    for(int i=0;i<8;i++) a=fmaf(rv[i],w0s[i*64+j],a);
    h1[j]=a/(1.f+__expf(-a));
  }
  unsigned short* hp = hid+(size_t)e*64;
  #pragma unroll 4
  for(int j=0;j<64;j++){
    float a=0.f;
    #pragma unroll
    for(int i=0;i<64;i++) a=fmaf(h1[i],w1s[i*64+j],a);
    hp[j]=f2bf(a/(1.f+__expf(-a)));
  }
}

// ---------------- cast+transpose both w2 [64 x 1088] -> w2t [1088 x 64] bf16 ----------------
__global__ __launch_bounds__(256) void k_cast2(
    const float* __restrict__ w2a, const float* __restrict__ w2b,
    unsigned short* __restrict__ ta, unsigned short* __restrict__ tb)
{
  int t=blockIdx.x*256+threadIdx.x;
  if(t>=2*1088*64) return;
  const float* src = (t<1088*64)? w2a : w2b;
  unsigned short* dst = (t<1088*64)? ta : tb;
  int u = (t<1088*64)? t : t-1088*64;
  int c=u>>6, k=u&63;
  dst[(size_t)c*64+k]=f2bf(src[(size_t)k*1088+c]);
}

// ---------------- FUSED: MFMA rw-GEMM (to LDS, f-major) + edge tensor product -> messages ----------------
// Block = 16 edges. Phase 1: rw[16 x RWLD] = hid[16x64] @ w2t^T via 16x16x32 MFMA.
// D scattered to LDS in f-major [edge][f][p] (pad FP=8/40) — scatter is free of line
// amplification in LDS (unlike the R6 HBM attempt). Phase 2: each (edge,f) thread reads
// its 34 weights as 5 contiguous ds_read_b128 and extracts paths with 1-op bf16->f32.
// MFMA layouts (HW-verified m89/m120): A-frag A[m=lane&15][k=quad*8+j];
// B-frag B[k=quad*8+j][n=lane&15]; D: row=quad*4+reg, col=lane&15.
template<bool L0>
__global__ __launch_bounds__(256,4) void k_tp_fused(
    const unsigned short* __restrict__ hlin, const float* __restrict__ Y,
    const unsigned short* __restrict__ hid, const unsigned short* __restrict__ w2t,
    const int* __restrict__ snd_s, unsigned short* __restrict__ msgs,
    int eb, int ecnt)
{
  constexpr int RWLD = L0 ? 128 : 1088;
  constexpr int FP   = L0 ? 8   : 40;     // padded paths per f
  constexpr int LSTR = 32*FP;             // shorts per edge (L0: 256 = 8KB tot; L1: 1280 = 40KB tot)
  __shared__ unsigned short rws[16*LSTR];
  int tid=threadIdx.x;
  int lane=tid&63, wave=tid>>6;
  int m16=lane&15, quad=lane>>4;
  int el0=blockIdx.x*16;
  // ---- phase 1: rw tile via MFMA, D -> LDS f-major ----
  {
    const unsigned short* Ab = hid + (size_t)el0*64;   // hid already offset by eb
    bf16x8 a0 = *(const bf16x8*)(Ab + m16*64 + quad*8);
    bf16x8 a1 = *(const bf16x8*)(Ab + m16*64 + 32 + quad*8);
    #pragma unroll 2
    for(int nt=wave; nt<RWLD/16; nt+=4){
      int col = nt*16 + m16;
      bf16x8 b0 = *(const bf16x8*)(w2t + (size_t)col*64 + quad*8);
      bf16x8 b1 = *(const bf16x8*)(w2t + (size_t)col*64 + 32 + quad*8);
      f32x4 acc = (f32x4){0.f,0.f,0.f,0.f};
      acc = __builtin_amdgcn_mfma_f32_16x16x32_bf16(a0,b0,acc,0,0,0);
      acc = __builtin_amdgcn_mfma_f32_16x16x32_bf16(a1,b1,acc,0,0,0);
      int f=col&31, p=col>>5;
      int dst = f*FP + p;
      #pragma unroll
      for(int r=0;r<4;r++)
        rws[(quad*4+r)*LSTR + dst] = f2bf(acc[r]);
    }
  }
  __syncthreads();
  // ---- phase 2: TP per (edge,f); wave's two halves take edges 8 apart ----
  int f=tid&31;
  int w=tid>>6, hb=(tid>>5)&1;
  #pragma unroll
  for(int sub=0;sub<2;sub++){
    int le = w + hb*8 + sub*4;
    int el=el0+le;
    if(el>=ecnt) continue;
    int j=eb+el;
    int s=snd_s[j];
    float hs[16];
    {
      const unsigned short* hp = hlin+(size_t)s*512+f*16;
      if (L0){
        hs[0]=bf2f(hp[0]);
        #pragma unroll
        for(int c=1;c<16;c++) hs[c]=0.f;
      } else {
        bf16x8 h0=*(const bf16x8*)hp;
        bf16x8 h1=*(const bf16x8*)(hp+8);
        #pragma unroll
        for(int c=0;c<8;c++){ hs[c]=bf2f((unsigned short)h0[c]); hs[8+c]=bf2f((unsigned short)h1[c]); }
      }
    }
    float yv[16];
    {
      const float4* yp=(const float4*)(Y+(size_t)j*16);
      float4 a=yp[0],b=yp[1],cc=yp[2],d=yp[3];
      yv[0]=a.x; yv[1]=a.y; yv[2]=a.z; yv[3]=a.w;
      yv[4]=b.x; yv[5]=b.y; yv[6]=b.z; yv[7]=b.w;
      yv[8]=cc.x; yv[9]=cc.y; yv[10]=cc.z; yv[11]=cc.w;
      yv[12]=d.x; yv[13]=d.y; yv[14]=d.z; yv[15]=d.w;
    }
    // vectorized rw read: 34 paths contiguous (padded to FP), 16B-aligned
    bf16x8 rr[5];
    {
      const unsigned short* rp = rws + le*LSTR + f*FP;
      rr[0]=*(const bf16x8*)rp;
      if constexpr (!L0){
        #pragma unroll
        for(int i=1;i<5;i++) rr[i]=*(const bf16x8*)(rp+i*8);
      }
    }
    float acc[16];
    #pragma unroll
    for(int c=0;c<16;c++) acc[c]=0.f;
    tp_paths<L0,0>(hs,yv,rr,acc);
    bf16x8 m0, m1;
    #pragma unroll
    for(int c=0;c<8;c++){
      m0[c]=(short)f2bf(acc[c]*0.0625f);
      m1[c]=(short)f2bf(acc[8+c]*0.0625f);
    }
    bf16x8* mp=(bf16x8*)(msgs+(size_t)el*512+f*16);
    mp[0]=m0; mp[1]=m1;
  }
}

// ---------------- CSR segment-sum of bf16 messages (no atomics) ----------------
__global__ __launch_bounds__(256) void k_seg_sum(
    const unsigned short* __restrict__ msgs, const int* __restrict__ row,
    float* __restrict__ agg, int eb, int ecnt, int N)
{
  int t=blockIdx.x*256+threadIdx.x;
  int n=t>>6, q=t&63;            // q indexes 8 consecutive floats; wave = 1 node
  if(n>=N) return;
  int lo=row[n], hi=row[n+1];
  int a0 = lo>eb ? lo : eb;
  int a1e = eb+ecnt;
  int a1 = hi<a1e ? hi : a1e;
  if(a0>=a1) return;
  float s[8];
  #pragma unroll
  for(int i=0;i<8;i++) s[i]=0.f;
  for(int j=a0;j<a1;j++){
    bf16x8 v=*(const bf16x8*)(msgs+(size_t)(j-eb)*512+q*8);
    #pragma unroll
    for(int i=0;i<8;i++) s[i]+=bf2f((unsigned short)v[i]);
  }
  float* ap=agg+(size_t)n*512+q*8;
  float4* a0p=(float4*)ap;
  float4 o0=a0p[0], o1=a0p[1];
  o0.x+=s[0]; o0.y+=s[1]; o0.z+=s[2]; o0.w+=s[3];
  o1.x+=s[4]; o1.y+=s[5]; o1.z+=s[6]; o1.w+=s[7];
  a0p[0]=o0; a0p[1]=o1;
}

// ---------------- node-wise symmetric tensor product (product basis) ----------------
__global__ __launch_bounds__(256) void k_tp_node(
    const float* __restrict__ in, float* __restrict__ out,
    const float* __restrict__ pb, const int* __restrict__ z, int N)
{
  int t=blockIdx.x*256+threadIdx.x;
  int n=t>>5, f=t&31;
  if(n>=N) return;
  float A[16];
  {
    const float4* p=(const float4*)(in+(size_t)n*512+f*16);
    float4 a=p[0],b=p[1],c=p[2],d=p[3];
    A[0]=a.x; A[1]=a.y; A[2]=a.z; A[3]=a.w;
    A[4]=b.x; A[5]=b.y; A[6]=b.z; A[7]=b.w;
    A[8]=c.x; A[9]=c.y; A[10]=c.z; A[11]=c.w;
    A[12]=d.x; A[13]=d.y; A[14]=d.z; A[15]=d.w;
  }
  float B2[16]; float B3[16];
  #pragma unroll
  for(int c=0;c<16;c++){ B2[c]=0.f; B3[c]=0.f; }
  tpn_paths<0>(A,A,B2);
  tpn_paths<0>(B2,A,B3);
  int zz=z[n];
  float wa=pb[zz*96+f], wb=pb[zz*96+32+f], wc=pb[zz*96+64+f];
  float o[16];
  #pragma unroll
  for(int c=0;c<16;c++) o[c]=wa*A[c]+wb*B2[c]+wc*B3[c];
  float4* op=(float4*)(out+(size_t)n*512+f*16);
  op[0]=make_float4(o[0],o[1],o[2],o[3]);
  op[1]=make_float4(o[4],o[5],o[6],o[7]);
  op[2]=make_float4(o[8],o[9],o[10],o[11]);
  op[3]=make_float4(o[12],o[13],o[14],o[15]);
}

// ---------------- merged readout: e0 dot + residual matmul ----------------
__global__ __launch_bounds__(256) void k_readout(
    const float* __restrict__ feats, const float* __restrict__ ro0,
    const float* __restrict__ res1, const int* __restrict__ z,
    float* __restrict__ e0, float* __restrict__ resid, int N)
{
  int t=blockIdx.x*256+threadIdx.x;
  int n=t>>5, g=t&31;
  if(n>=N) return;
  const float* wp=res1+(size_t)z[n]*1024;
  float a=0.f;
  #pragma unroll 8
  for(int f=0;f<32;f++) a=fmaf(feats[(size_t)n*512+f*16], wp[(f<<5)+g], a);
  resid[(size_t)n*32+g]=a;
  if(g==0){
    float b=0.f;
    #pragma unroll 8
    for(int f=0;f<32;f++) b=fmaf(feats[(size_t)n*512+f*16], ro0[f], b);
    e0[n]=b;
  }
}

__global__ __launch_bounds__(256) void k_final(
    const float* __restrict__ h, const float* __restrict__ resid,
    const float* __restrict__ e0a, const float* __restrict__ ro1a,
    const float* __restrict__ ro1b, float* __restrict__ out, int N)
{
  int t=blockIdx.x*256+threadIdx.x;
  float val=0.f;
  if (t<N){
    float sc[32];
    #pragma unroll 8
    for(int f=0;f<32;f++) sc[f]=h[(size_t)t*512+f*16]+resid[(size_t)t*32+f];
    float e1=0.f;
    #pragma unroll
    for(int j=0;j<16;j++){
      float a=0.f;
      #pragma unroll
      for(int f=0;f<32;f++) a=fmaf(sc[f],ro1a[f*16+j],a);
      float s=a/(1.f+__expf(-a));
      e1=fmaf(s,ro1b[j],e1);
    }
    val = -1.5f + 2.0f*(e0a[t]+e1) - 10.0f;
  }
  __shared__ float red[256];
  red[threadIdx.x]=val;
  __syncthreads();
  for(int s=128;s>0;s>>=1){
    if(threadIdx.x<s) red[threadIdx.x]+=red[threadIdx.x+s];
    __syncthreads();
  }
  if(threadIdx.x==0) atomicAdd(out, red[0]);
}

// ---------------- host orchestration ----------------
extern "C" void kernel_launch(void* const* d_in, const int* in_sizes, int n_in,
                              void* d_out, int out_size, void* d_ws, size_t ws_size,
                              hipStream_t stream)
{
  const float* vec   =(const float*)d_in[0];
  const int*   zarr  =(const int*)  d_in[1];
  const int*   snd   =(const int*)  d_in[2];
  const int*   rcv   =(const int*)  d_in[3];
  const float* embed =(const float*)d_in[4];
  const float* r0w0  =(const float*)d_in[5];
  const float* r0w1  =(const float*)d_in[6];
  const float* r0w2  =(const float*)d_in[7];
  const float* up0   =(const float*)d_in[8];
  const float* post0 =(const float*)d_in[9];
  const float* pb0   =(const float*)d_in[10];
  const float* pblin0=(const float*)d_in[11];
  const float* r1w0  =(const float*)d_in[12];
  const float* r1w1  =(const float*)d_in[13];
  const float* r1w2  =(const float*)d_in[14];
  const float* up1   =(const float*)d_in[15];
  const float* post1 =(const float*)d_in[16];
  const float* pb1   =(const float*)d_in[17];
  const float* pblin1=(const float*)d_in[18];
  const float* sel0  =(const float*)d_in[19];
  const float* ro0   =(const float*)d_in[20];
  const float* res1  =(const float*)d_in[21];
  const float* ro1a  =(const float*)d_in[22];
  const float* ro1b  =(const float*)d_in[23];

  const int E = in_sizes[0]/3;
  const int N = in_sizes[1];
  const int Epad = (E+63)&~63;

  char* ws=(char*)d_ws;
  size_t o=0;
  auto alloc=[&](size_t bytes)->char*{
    char* p=ws+o;
    o=(o+bytes+255)&~(size_t)255;
    return p;
  };
  int*   deg  =(int*)  alloc((size_t)N*4);
  int*   rowp =(int*)  alloc((size_t)(N+1)*4);
  int*   cur  =(int*)  alloc((size_t)N*4);
  int*   eid  =(int*)  alloc((size_t)E*4);
  int*   snd_s=(int*)  alloc((size_t)E*4);
  float* Yb   =(float*)alloc((size_t)E*16*4);
  float* radb =(float*)alloc((size_t)E*8*4);
  unsigned short* hidb=(unsigned short*)alloc((size_t)(Epad+16)*64*2);
  unsigned short* w2t0=(unsigned short*)alloc((size_t)1088*64*2);
  unsigned short* w2t1=(unsigned short*)alloc((size_t)1088*64*2);
  unsigned short* hl16=(unsigned short*)alloc((size_t)N*512*2);
  float* feats=(float*)alloc((size_t)N*512*4);
  float* bufA =(float*)alloc((size_t)N*512*4);
  float* bufB =(float*)alloc((size_t)N*512*4);
  float* bufC =(float*)alloc((size_t)N*512*4);
  float* e0b  =(float*)alloc((size_t)N*4);
  float* residb=(float*)alloc((size_t)N*32*4);
  char*  dyn  = ws+o;
  size_t remain = ws_size>o ? ws_size-o : 0;

  dim3 tb(256);
  dim3 nblk((unsigned)((N*32+255)/256));
  dim3 eblk((unsigned)((E+255)/256));
  dim3 qblk((unsigned)((N*64+255)/256));

  // CSR build (receiver-sorted edge order)
  hipMemsetAsync(deg,0,(size_t)N*4,stream);
  k_count<<<eblk,tb,0,stream>>>(rcv,deg,E);
  k_scan<<<dim3(1),dim3(1024),0,stream>>>(deg,rowp,cur,N);
  k_fill<<<eblk,tb,0,stream>>>(rcv,cur,eid,E);

  k_edge_setup<<<eblk,tb,0,stream>>>(vec,snd,eid,Yb,radb,snd_s,E);
  k_node_init<<<nblk,tb,0,stream>>>(embed,zarr,feats,N);

  // cast+transpose radial-MLP final weights to bf16 (per launch)
  k_cast2<<<dim3((2*1088*64+255)/256),tb,0,stream>>>(r0w2,r1w2,w2t0,w2t1);

  auto run_edges=[&](bool l0, const unsigned short* hlin, const unsigned short* w2t, float* agg){
    // per-edge workspace: msgs only (rw lives in LDS inside the fused kernel)
    long rows = (long)(remain/1024);
    rows -= rows%64;
    if (rows>(long)Epad) rows=Epad;
    if (rows<64) rows=64;
    unsigned short* msgsb = (unsigned short*)dyn;
    for(long eb=0;eb<E;eb+=rows){
      long cnt = E-eb; if(cnt>rows) cnt=rows;
      dim3 g2((unsigned)((cnt+15)/16));
      if(l0) k_tp_fused<true ><<<g2,tb,0,stream>>>(hlin,Yb,hidb+(size_t)eb*64,w2t,snd_s,msgsb,(int)eb,(int)cnt);
      else   k_tp_fused<false><<<g2,tb,0,stream>>>(hlin,Yb,hidb+(size_t)eb*64,w2t,snd_s,msgsb,(int)eb,(int)cnt);
      k_seg_sum<<<qblk,tb,0,stream>>>(msgsb,rowp,agg,(int)eb,(int)cnt,N);
    }
  };

  // ---- layer 0 ----
  k_lin16<<<nblk,tb,0,stream>>>(feats,hl16,up0,N);
  k_radial<<<eblk,tb,0,stream>>>(radb,r0w0,r0w1,hidb,E);
  hipMemsetAsync(bufB,0,(size_t)N*512*4,stream);
  run_edges(true,hl16,w2t0,bufB);
  k_lin<<<nblk,tb,0,stream>>>(bufB,bufC,post0,(const int*)nullptr,0,N);
  k_lin<<<nblk,tb,0,stream>>>(bufC,bufA,sel0,zarr,4096,N);
  k_tp_node<<<nblk,tb,0,stream>>>(bufA,bufB,pb0,zarr,N);
  k_lin<<<nblk,tb,0,stream>>>(bufB,feats,pblin0,(const int*)nullptr,0,N);
  k_readout<<<nblk,tb,0,stream>>>(feats,ro0,res1,zarr,e0b,residb,N);

  // ---- layer 1 ----
  k_lin16<<<nblk,tb,0,stream>>>(feats,hl16,up1,N);
  k_radial<<<eblk,tb,0,stream>>>(radb,r1w0,r1w1,hidb,E);
  hipMemsetAsync(bufC,0,(size_t)N*512*4,stream);
  run_edges(false,hl16,w2t1,bufC);
  k_lin<<<nblk,tb,0,stream>>>(bufC,bufB,post1,(const int*)nullptr,0,N);
  k_tp_node<<<nblk,tb,0,stream>>>(bufB,bufA,pb1,zarr,N);
  k_lin<<<nblk,tb,0,stream>>>(bufA,bufC,pblin1,(const int*)nullptr,0,N);

  hipMemsetAsync(d_out,0,4,stream);
  k_final<<<dim3((N+255)/256),tb,0,stream>>>(bufC,residb,e0b,ro1a,ro1b,(float*)d_out,N);
}

// Round 12
// 1031.773 us; speedup vs baseline: 2.2771x; 2.2771x over previous
//
#include <hip/hip_runtime.h>
#include <math.h>

// ---------------- static config ----------------
#define NF 32
#define NPATHS 34

typedef __attribute__((ext_vector_type(8))) short bf16x8;
typedef __attribute__((ext_vector_type(4))) float f32x4;

__device__ __forceinline__ unsigned short f2bf(float v){
  unsigned u = __float_as_uint(v);
  u += 0x7fffu + ((u>>16)&1u);
  return (unsigned short)(u>>16);
}
__device__ __forceinline__ float bf2f(unsigned short h){
  return __uint_as_float(((unsigned)h)<<16);
}

struct PathTab { int l1[NPATHS]; int l2[NPATHS]; int l3[NPATHS]; };
constexpr PathTab mkpaths(){
  PathTab t{}; int n=0;
  for(int a=0;a<=3;a++)for(int b=0;b<=3;b++)for(int c=0;c<=3;c++){
    int lo = a>b ? a-b : b-a;
    if(c>=lo && c<=a+b){ t.l1[n]=a; t.l2[n]=b; t.l3[n]=c; n++; }
  }
  return t;
}
constexpr PathTab PT = mkpaths();

// ---------------- compile-time Wigner-3j (exact replica of reference math) ----------------
struct FactT { double v[22]; };
constexpr FactT mkfactT(){ FactT f{}; f.v[0]=1.0; for(int i=1;i<22;i++) f.v[i]=f.v[i-1]*(double)i; return f; }
constexpr FactT FT = mkfactT();
constexpr double cfact(int n){ return FT.v[n]; }

constexpr double csqrt(double x){
  if(x<=0.0) return 0.0;
  double g = x<1.0 ? 1.0 : x;
  for(int i=0;i<40;i++) g=0.5*(g+x/g);
  return g;
}

constexpr double su2cg(int j1,int j2,int j3,int m1,int m2){
  int m3=m1+m2;
  if(m3<-j3||m3>j3) return 0.0;
  double pref = (double)(2*j3+1)*cfact(j3+j1-j2)*cfact(j3-j1+j2)*cfact(j1+j2-j3)/cfact(j1+j2+j3+1);
  pref *= cfact(j3+m3)*cfact(j3-m3)*cfact(j1-m1)*cfact(j1+m1)*cfact(j2-m2)*cfact(j2+m2);
  pref = csqrt(pref);
  int k0=0; if(j2-j3-m1>k0)k0=j2-j3-m1; if(j1-j3+m2>k0)k0=j1-j3+m2;
  int k1=j1+j2-j3; if(j1-m1<k1)k1=j1-m1; if(j2+m2<k1)k1=j2+m2;
  double s=0.0;
  for(int k=k0;k<=k1;k++){
    double d = cfact(k)*cfact(j1+j2-j3-k)*cfact(j1-m1-k)*cfact(j2+m2-k)*cfact(j3-j2+m1+k)*cfact(j3-j1-m2+k);
    s += (k&1)? -1.0/d : 1.0/d;
  }
  return pref*s;
}

struct ccd { double x, y; };
constexpr ccd cqval(int l,int r,int col){
  const double is2 = 0.70710678118654752440;
  double re=0.0, im=0.0;
  if (r<l){ if (col==2*l-r) re=is2; else if (col==r) im=-is2; }
  else if (r==l){ if (col==l) re=1.0; }
  else { double s = ((r-l)&1)? -1.0:1.0;
         if (col==r) re=s*is2; else if (col==2*l-r) im=s*is2; }
  ccd v{re,im};
  switch(l&3){           // multiply by (-i)^l
    case 1: return ccd{ v.y, -v.x };
    case 2: return ccd{-v.x, -v.y };
    case 3: return ccd{-v.y,  v.x };
    default: return v;
  }
}

constexpr double w3entry(int l1,int l2,int l3,int i,int j,int k){
  double re=0.0;
  for(int a=0;a<2*l1+1;a++){
    ccd qa=cqval(l1,a,i); if(qa.x==0.0&&qa.y==0.0) continue;
    for(int b=0;b<2*l2+1;b++){
      ccd qb=cqval(l2,b,j); if(qb.x==0.0&&qb.y==0.0) continue;
      int m1=a-l1, m2=b-l2, m3=m1+m2;
      if(m3<-l3||m3>l3) continue;
      int c=m3+l3;
      double cg=su2cg(l1,l2,l3,m1,m2); if(cg==0.0) continue;
      ccd qc=cqval(l3,c,k); qc.y=-qc.y;   // conj
      if(qc.x==0.0&&qc.y==0.0) continue;
      ccd ab{qa.x*qb.x-qa.y*qb.y, qa.x*qb.y+qa.y*qb.x};
      re += cg*(ab.x*qc.x - ab.y*qc.y);
    }
  }
  return re;
}

template<int L1,int L2,int L3> struct W3Arr { float v[(2*L1+1)*(2*L2+1)*(2*L3+1)]; };
template<int L1,int L2,int L3> constexpr W3Arr<L1,L2,L3> mkW3(double scale){
  W3Arr<L1,L2,L3> r{};
  for(int i=0;i<2*L1+1;i++)
    for(int j=0;j<2*L2+1;j++)
      for(int k=0;k<2*L3+1;k++)
        r.v[(i*(2*L2+1)+j)*(2*L3+1)+k] = (float)(w3entry(L1,L2,L3,i,j,k)*scale);
  return r;
}
template<int L1,int L2,int L3> constexpr W3Arr<L1,L2,L3> W3V = mkW3<L1,L2,L3>(1.0);
template<int L1,int L2,int L3> constexpr W3Arr<L1,L2,L3> W3N = mkW3<L1,L2,L3>(1.0/csqrt(2.0*L3+1.0));

// SH recursion scales (replica of reference _sh_scales, float64 like numpy)
struct SCt { double sc2, sc3; };
constexpr SCt mksc(){
  double v0=0.2,v1=-0.6,v2=0.7;
  double nv=csqrt(v0*v0+v1*v1+v2*v2);
  double s3=csqrt(3.0);
  double y1[3]={s3*v0/nv, s3*v1/nv, s3*v2/nv};
  double t2[5]={0,0,0,0,0}; double n2=0.0;
  for(int c=0;c<5;c++){
    double s=0.0;
    for(int a=0;a<3;a++)for(int b=0;b<3;b++) s += w3entry(1,1,2,a,b,c)*y1[a]*y1[b];
    t2[c]=s; n2+=s*s;
  }
  double sc2=csqrt(5.0)/csqrt(n2);
  double y2[5]={sc2*t2[0],sc2*t2[1],sc2*t2[2],sc2*t2[3],sc2*t2[4]};
  double n3=0.0;
  for(int c=0;c<7;c++){
    double s=0.0;
    for(int a=0;a<5;a++)for(int b=0;b<3;b++) s += w3entry(2,1,3,a,b,c)*y2[a]*y1[b];
    n3+=s*s;
  }
  double sc3=csqrt(7.0)/csqrt(n3);
  return SCt{sc2,sc3};
}
constexpr SCt SCV = mksc();

// ---------------- template-unrolled TP with literal W3J, true-zero elision ----------------
template<bool NORM,int l1,int l2,int l3,int A,int B,int C>
__device__ __forceinline__ void w3term(const float* __restrict__ x, const float* __restrict__ y,
                                       float rv, float* __restrict__ acc){
  constexpr float w = NORM ? W3N<l1,l2,l3>.v[(A*(2*l2+1)+B)*(2*l3+1)+C]
                           : W3V<l1,l2,l3>.v[(A*(2*l2+1)+B)*(2*l3+1)+C];
  if constexpr (w!=0.0f)
    acc[l3*l3+C] = fmaf(w, x[l1*l1+A]*y[l2*l2+B]*rv, acc[l3*l3+C]);
}
template<bool NORM,int l1,int l2,int l3,int A,int B,int C>
__device__ __forceinline__ void w3loopC(const float* x,const float* y,float rv,float* acc){
  if constexpr (C<2*l3+1){
    w3term<NORM,l1,l2,l3,A,B,C>(x,y,rv,acc);
    w3loopC<NORM,l1,l2,l3,A,B,C+1>(x,y,rv,acc);
  }
}
template<bool NORM,int l1,int l2,int l3,int A,int B>
__device__ __forceinline__ void w3loopB(const float* x,const float* y,float rv,float* acc){
  if constexpr (B<2*l2+1){
    w3loopC<NORM,l1,l2,l3,A,B,0>(x,y,rv,acc);
    w3loopB<NORM,l1,l2,l3,A,B+1>(x,y,rv,acc);
  }
}
template<bool NORM,int l1,int l2,int l3,int A>
__device__ __forceinline__ void w3loopA(const float* x,const float* y,float rv,float* acc){
  if constexpr (A<2*l1+1){
    w3loopB<NORM,l1,l2,l3,A,0>(x,y,rv,acc);
    w3loopA<NORM,l1,l2,l3,A+1>(x,y,rv,acc);
  }
}

template<bool L0,int P>
__device__ __forceinline__ void tp_paths(const float* hs,const float* yv,
                                         const unsigned short* rp, float* acc){
  if constexpr (P<NPATHS){
    constexpr int l1=PT.l1[P], l2=PT.l2[P], l3=PT.l3[P];
    if constexpr (!(L0 && l1!=0)){
      float rv = bf2f(rp[P*32]);
      w3loopA<false,l1,l2,l3,0>(hs,yv,rv,acc);
    }
    tp_paths<L0,P+1>(hs,yv,rp,acc);
  }
}

template<int P>
__device__ __forceinline__ void tpn_paths(const float* x,const float* y,float* o){
  if constexpr (P<NPATHS){
    constexpr int l1=PT.l1[P], l2=PT.l2[P], l3=PT.l3[P];
    w3loopA<true,l1,l2,l3,0>(x,y,1.0f,o);
    tpn_paths<P+1>(x,y,o);
  }
}

// ---------------- CSR build: degree count, scan, fill ----------------
__global__ __launch_bounds__(256) void k_count(
    const int* __restrict__ rcv, int* __restrict__ deg, int E)
{
  int e=blockIdx.x*256+threadIdx.x;
  if(e>=E) return;
  atomicAdd(&deg[rcv[e]],1);
}

#define SCAN_PER 32
__global__ __launch_bounds__(1024) void k_scan(
    const int* __restrict__ deg, int* __restrict__ row,
    int* __restrict__ cur, int N)
{
  __shared__ int part[1024];
  int t=threadIdx.x;
  int per=(N+1023)/1024; if(per>SCAN_PER) per=SCAN_PER;
  int base=t*per;
  int loc[SCAN_PER];
  int s=0;
  for(int i=0;i<per;i++){ int idx=base+i; int v=(idx<N)? deg[idx]:0; loc[i]=s; s+=v; }
  part[t]=s;
  __syncthreads();
  for(int off=1;off<1024;off<<=1){
    int v=(t>=off)? part[t-off]:0;
    __syncthreads();
    part[t]+=v;
    __syncthreads();
  }
  int ex=(t==0)?0:part[t-1];
  for(int i=0;i<per;i++){
    int idx=base+i;
    if(idx<N){ int r=ex+loc[i]; row[idx]=r; cur[idx]=r; }
  }
  if(t==1023) row[N]=part[1023];
}

__global__ __launch_bounds__(256) void k_fill(
    const int* __restrict__ rcv, int* __restrict__ cur,
    int* __restrict__ eid, int E)
{
  int e=blockIdx.x*256+threadIdx.x;
  if(e>=E) return;
  int pos=atomicAdd(&cur[rcv[e]],1);
  eid[pos]=e;
}

// ---------------- per-edge geometry (receiver-sorted order): SH + radial basis ----------------
__global__ __launch_bounds__(256) void k_edge_setup(
    const float* __restrict__ vec, const int* __restrict__ snd,
    const int* __restrict__ eid, float* __restrict__ Y,
    float* __restrict__ rad, int* __restrict__ snd_s, int E)
{
  int j = blockIdx.x*256+threadIdx.x;
  if (j>=E) return;
  int e = eid[j];
  snd_s[j]=snd[e];
  float vx=vec[3*e], vy=vec[3*e+1], vz=vec[3*e+2];
  float r=sqrtf(vx*vx+vy*vy+vz*vz);
  float inv=1.0f/fmaxf(r,1e-9f);
  float y[16];
  y[0]=1.0f;
  const float s3=1.7320508075688772f;
  y[1]=s3*vx*inv; y[2]=s3*vy*inv; y[3]=s3*vz*inv;
  constexpr float sc2=(float)SCV.sc2, sc3=(float)SCV.sc3;
  {
    float t[16];
    #pragma unroll
    for(int c=0;c<16;c++) t[c]=0.f;
    w3loopA<false,1,1,2,0>(y,y,1.0f,t);     // t[4..8] = einsum(w112, y1, y1)
    #pragma unroll
    for(int c=0;c<5;c++) y[4+c]=sc2*t[4+c];
    w3loopA<false,2,1,3,0>(y,y,1.0f,t);     // t[9..15] = einsum(w213, y2, y1)
    #pragma unroll
    for(int c=0;c<7;c++) y[9+c]=sc3*t[9+c];
  }
  float4* Yp=(float4*)(Y+(size_t)j*16);
  Yp[0]=make_float4(y[0],y[1],y[2],y[3]);
  Yp[1]=make_float4(y[4],y[5],y[6],y[7]);
  Yp[2]=make_float4(y[8],y[9],y[10],y[11]);
  Yp[3]=make_float4(y[12],y[13],y[14],y[15]);
  float x = r*0.2f;
  float env=0.f;
  if (x<1.0f){
    float x2=x*x; float x4=x2*x2; float x5=x4*x;
    env = 1.0f - 21.0f*x5 + 35.0f*x5*x - 15.0f*x5*x2;
  }
  const float cb = 0.632455532033675866f; // sqrt(2/5)
  float base = inv*env*cb;
  #pragma unroll
  for(int n=1;n<=8;n++)
    rad[(size_t)j*8 + n-1] = base*sinf(3.14159265358979323846f * x * (float)n);
}

// ---------------- node init: scalar embedding ----------------
__global__ __launch_bounds__(256) void k_node_init(
    const float* __restrict__ embed, const int* __restrict__ z,
    float* __restrict__ feats, int N)
{
  int t = blockIdx.x*256+threadIdx.x;
  int n=t>>5, f=t&31;
  if(n>=N) return;
  float v = embed[z[n]*NF + f];
  float4* p=(float4*)(feats + (size_t)n*512 + f*16);
  p[0]=make_float4(v,0.f,0.f,0.f);
  p[1]=make_float4(0.f,0.f,0.f,0.f);
  p[2]=make_float4(0.f,0.f,0.f,0.f);
  p[3]=make_float4(0.f,0.f,0.f,0.f);
}

// ---------------- per-l channel-mixing linear (f32 out) ----------------
__global__ __launch_bounds__(256) void k_lin(
    const float* __restrict__ in, float* __restrict__ out,
    const float* __restrict__ w, const int* __restrict__ z, int zstride, int N)
{
  int t=blockIdx.x*256+threadIdx.x;
  int n=t>>5, g=t&31;
  if(n>=N) return;
  const float* wp = w + (z ? (size_t)z[n]*(size_t)zstride : 0);
  const float* ip = in + (size_t)n*512;
  float acc[16];
  #pragma unroll
  for(int c=0;c<16;c++) acc[c]=0.f;
  #pragma unroll 8
  for(int f=0; f<NF; f++){
    const float4* xp = (const float4*)(ip + f*16);
    float4 x0=xp[0], x1=xp[1], x2=xp[2], x3=xp[3];
    float w0v=wp[(f<<5)+g], w1v=wp[1024+(f<<5)+g], w2v=wp[2048+(f<<5)+g], w3v=wp[3072+(f<<5)+g];
    acc[0]  = fmaf(x0.x,w0v,acc[0]);
    acc[1]  = fmaf(x0.y,w1v,acc[1]);
    acc[2]  = fmaf(x0.z,w1v,acc[2]);
    acc[3]  = fmaf(x0.w,w1v,acc[3]);
    acc[4]  = fmaf(x1.x,w2v,acc[4]);
    acc[5]  = fmaf(x1.y,w2v,acc[5]);
    acc[6]  = fmaf(x1.z,w2v,acc[6]);
    acc[7]  = fmaf(x1.w,w2v,acc[7]);
    acc[8]  = fmaf(x2.x,w2v,acc[8]);
    acc[9]  = fmaf(x2.y,w3v,acc[9]);
    acc[10] = fmaf(x2.z,w3v,acc[10]);
    acc[11] = fmaf(x2.w,w3v,acc[11]);
    acc[12] = fmaf(x3.x,w3v,acc[12]);
    acc[13] = fmaf(x3.y,w3v,acc[13]);
    acc[14] = fmaf(x3.z,w3v,acc[14]);
    acc[15] = fmaf(x3.w,w3v,acc[15]);
  }
  float4* op=(float4*)(out + (size_t)n*512 + g*16);
  op[0]=make_float4(acc[0],acc[1],acc[2],acc[3]);
  op[1]=make_float4(acc[4],acc[5],acc[6],acc[7]);
  op[2]=make_float4(acc[8],acc[9],acc[10],acc[11]);
  op[3]=make_float4(acc[12],acc[13],acc[14],acc[15]);
}

// ---------------- per-l channel-mixing linear (bf16 out, for fused-TP input) ----------------
__global__ __launch_bounds__(256) void k_lin16(
    const float* __restrict__ in, unsigned short* __restrict__ out,
    const float* __restrict__ w, int N)
{
  int t=blockIdx.x*256+threadIdx.x;
  int n=t>>5, g=t&31;
  if(n>=N) return;
  const float* wp = w;
  const float* ip = in + (size_t)n*512;
  float acc[16];
  #pragma unroll
  for(int c=0;c<16;c++) acc[c]=0.f;
  #pragma unroll 8
  for(int f=0; f<NF; f++){
    const float4* xp = (const float4*)(ip + f*16);
    float4 x0=xp[0], x1=xp[1], x2=xp[2], x3=xp[3];
    float w0v=wp[(f<<5)+g], w1v=wp[1024+(f<<5)+g], w2v=wp[2048+(f<<5)+g], w3v=wp[3072+(f<<5)+g];
    acc[0]  = fmaf(x0.x,w0v,acc[0]);
    acc[1]  = fmaf(x0.y,w1v,acc[1]);
    acc[2]  = fmaf(x0.z,w1v,acc[2]);
    acc[3]  = fmaf(x0.w,w1v,acc[3]);
    acc[4]  = fmaf(x1.x,w2v,acc[4]);
    acc[5]  = fmaf(x1.y,w2v,acc[5]);
    acc[6]  = fmaf(x1.z,w2v,acc[6]);
    acc[7]  = fmaf(x1.w,w2v,acc[7]);
    acc[8]  = fmaf(x2.x,w2v,acc[8]);
    acc[9]  = fmaf(x2.y,w3v,acc[9]);
    acc[10] = fmaf(x2.z,w3v,acc[10]);
    acc[11] = fmaf(x2.w,w3v,acc[11]);
    acc[12] = fmaf(x3.x,w3v,acc[12]);
    acc[13] = fmaf(x3.y,w3v,acc[13]);
    acc[14] = fmaf(x3.z,w3v,acc[14]);
    acc[15] = fmaf(x3.w,w3v,acc[15]);
  }
  bf16x8 o0,o1;
  #pragma unroll
  for(int c=0;c<8;c++){ o0[c]=(short)f2bf(acc[c]); o1[c]=(short)f2bf(acc[8+c]); }
  bf16x8* op=(bf16x8*)(out + (size_t)n*512 + g*16);
  op[0]=o0; op[1]=o1;
}

// ---------------- radial MLP hidden layers (bf16 output) ----------------
__global__ __launch_bounds__(256) void k_radial(
    const float* __restrict__ rad, const float* __restrict__ w0,
    const float* __restrict__ w1, unsigned short* __restrict__ hid, int E)
{
  __shared__ float w0s[8*64];
  __shared__ float w1s[64*64];
  int tid=threadIdx.x;
  for(int i=tid;i<512;i+=256) w0s[i]=w0[i];
  for(int i=tid;i<4096;i+=256) w1s[i]=w1[i];
  __syncthreads();
  int e=blockIdx.x*256+tid;
  if(e>=E) return;
  const float4* rp=(const float4*)(rad+(size_t)e*8);
  float4 ra=rp[0], rb=rp[1];
  float rv[8]={ra.x,ra.y,ra.z,ra.w,rb.x,rb.y,rb.z,rb.w};
  float h1[64];
  #pragma unroll 8
  for(int j=0;j<64;j++){
    float a=0.f;
    #pragma unroll
    for(int i=0;i<8;i++) a=fmaf(rv[i],w0s[i*64+j],a);
    h1[j]=a/(1.f+__expf(-a));
  }
  unsigned short* hp = hid+(size_t)e*64;
  #pragma unroll 4
  for(int j=0;j<64;j++){
    float a=0.f;
    #pragma unroll
    for(int i=0;i<64;i++) a=fmaf(h1[i],w1s[i*64+j],a);
    hp[j]=f2bf(a/(1.f+__expf(-a)));
  }
}

// ---------------- cast+transpose both w2 [64 x 1088] -> w2t [1088 x 64] bf16 ----------------
__global__ __launch_bounds__(256) void k_cast2(
    const float* __restrict__ w2a, const float* __restrict__ w2b,
    unsigned short* __restrict__ ta, unsigned short* __restrict__ tb)
{
  int t=blockIdx.x*256+threadIdx.x;
  if(t>=2*1088*64) return;
  const float* src = (t<1088*64)? w2a : w2b;
  unsigned short* dst = (t<1088*64)? ta : tb;
  int u = (t<1088*64)? t : t-1088*64;
  int c=u>>6, k=u&63;
  dst[(size_t)c*64+k]=f2bf(src[(size_t)k*1088+c]);
}

// ---------------- FUSED: MFMA rw-GEMM (to LDS) + edge tensor product -> messages ----------------
// Block = 16 edges. Phase 1: rw[16 x RWLD] = hid[16x64] @ w2t^T via 16x16x32 MFMA,
// D -> LDS [edge][col] (col = p*32+f). LSTR ≡ 4 mod 16 so the 4 D-quads land on
// disjoint bank quartets; phase-2 half-waves take edges 8 apart — measured 0 conflicts (R10).
// snd_s for both sub-rounds is loaded BEFORE phase 1 so the 2-level gather chain's first
// level overlaps the MFMA phase. NO launch_bounds min-waves (R11: forcing VGPR=64 spilled 6.8GB).
// MFMA layouts (HW-verified m89/m120): A-frag A[m=lane&15][k=quad*8+j];
// B-frag B[k=quad*8+j][n=lane&15]; D: row=quad*4+reg, col=lane&15.
template<bool L0>
__global__ __launch_bounds__(256) void k_tp_fused(
    const unsigned short* __restrict__ hlin, const float* __restrict__ Y,
    const unsigned short* __restrict__ hid, const unsigned short* __restrict__ w2t,
    const int* __restrict__ snd_s, unsigned short* __restrict__ msgs,
    int eb, int ecnt)
{
  constexpr int RWLD = L0 ? 128 : 1088;
  constexpr int LSTR = L0 ? 132 : 1092;
  __shared__ unsigned short rws[16*LSTR];
  int tid=threadIdx.x;
  int lane=tid&63, wave=tid>>6;
  int m16=lane&15, quad=lane>>4;
  int el0=blockIdx.x*16;
  // hoist sender ids for both phase-2 sub-rounds (first level of the gather chain)
  int f=tid&31;
  int w=tid>>6, hb=(tid>>5)&1;
  int le_base = w + hb*8;
  int el_s0 = el0 + le_base;
  int el_s1 = el0 + le_base + 4;
  int s0 = (el_s0<ecnt)? snd_s[eb+el_s0] : 0;
  int s1 = (el_s1<ecnt)? snd_s[eb+el_s1] : 0;
  // ---- phase 1: rw tile via MFMA, D -> LDS ----
  {
    const unsigned short* Ab = hid + (size_t)el0*64;   // hid already offset by eb
    bf16x8 a0 = *(const bf16x8*)(Ab + m16*64 + quad*8);
    bf16x8 a1 = *(const bf16x8*)(Ab + m16*64 + 32 + quad*8);
    #pragma unroll 2
    for(int nt=wave; nt<RWLD/16; nt+=4){
      int col = nt*16 + m16;
      bf16x8 b0 = *(const bf16x8*)(w2t + (size_t)col*64 + quad*8);
      bf16x8 b1 = *(const bf16x8*)(w2t + (size_t)col*64 + 32 + quad*8);
      f32x4 acc = (f32x4){0.f,0.f,0.f,0.f};
      acc = __builtin_amdgcn_mfma_f32_16x16x32_bf16(a0,b0,acc,0,0,0);
      acc = __builtin_amdgcn_mfma_f32_16x16x32_bf16(a1,b1,acc,0,0,0);
      #pragma unroll
      for(int r=0;r<4;r++)
        rws[(quad*4+r)*LSTR + col] = f2bf(acc[r]);
    }
  }
  __syncthreads();
  // ---- phase 2: TP per (edge,f); wave's two halves take edges 8 apart ----
  #pragma unroll
  for(int sub=0;sub<2;sub++){
    int le = le_base + sub*4;
    int el=el0+le;
    if(el>=ecnt) continue;
    int j=eb+el;
    int s = (sub==0)? s0 : s1;
    float hs[16];
    {
      const unsigned short* hp = hlin+(size_t)s*512+f*16;
      if (L0){
        hs[0]=bf2f(hp[0]);
        #pragma unroll
        for(int c=1;c<16;c++) hs[c]=0.f;
      } else {
        bf16x8 h0=*(const bf16x8*)hp;
        bf16x8 h1=*(const bf16x8*)(hp+8);
        #pragma unroll
        for(int c=0;c<8;c++){ hs[c]=bf2f((unsigned short)h0[c]); hs[8+c]=bf2f((unsigned short)h1[c]); }
      }
    }
    float yv[16];
    {
      const float4* yp=(const float4*)(Y+(size_t)j*16);
      float4 a=yp[0],b=yp[1],cc=yp[2],d=yp[3];
      yv[0]=a.x; yv[1]=a.y; yv[2]=a.z; yv[3]=a.w;
      yv[4]=b.x; yv[5]=b.y; yv[6]=b.z; yv[7]=b.w;
      yv[8]=cc.x; yv[9]=cc.y; yv[10]=cc.z; yv[11]=cc.w;
      yv[12]=d.x; yv[13]=d.y; yv[14]=d.z; yv[15]=d.w;
    }
    const unsigned short* rp = rws + le*LSTR + f;
    float acc[16];
    #pragma unroll
    for(int c=0;c<16;c++) acc[c]=0.f;
    tp_paths<L0,0>(hs,yv,rp,acc);
    bf16x8 m0, m1;
    #pragma unroll
    for(int c=0;c<8;c++){
      m0[c]=(short)f2bf(acc[c]*0.0625f);
      m1[c]=(short)f2bf(acc[8+c]*0.0625f);
    }
    bf16x8* mp=(bf16x8*)(msgs+(size_t)el*512+f*16);
    mp[0]=m0; mp[1]=m1;
  }
}

// ---------------- CSR segment-sum of bf16 messages (no atomics) ----------------
__global__ __launch_bounds__(256) void k_seg_sum(
    const unsigned short* __restrict__ msgs, const int* __restrict__ row,
    float* __restrict__ agg, int eb, int ecnt, int N)
{
  int t=blockIdx.x*256+threadIdx.x;
  int n=t>>6, q=t&63;            // q indexes 8 consecutive floats; wave = 1 node
  if(n>=N) return;
  int lo=row[n], hi=row[n+1];
  int a0 = lo>eb ? lo : eb;
  int a1e = eb+ecnt;
  int a1 = hi<a1e ? hi : a1e;
  if(a0>=a1) return;
  float s[8];
  #pragma unroll
  for(int i=0;i<8;i++) s[i]=0.f;
  for(int j=a0;j<a1;j++){
    bf16x8 v=*(const bf16x8*)(msgs+(size_t)(j-eb)*512+q*8);
    #pragma unroll
    for(int i=0;i<8;i++) s[i]+=bf2f((unsigned short)v[i]);
  }
  float* ap=agg+(size_t)n*512+q*8;
  float4* a0p=(float4*)ap;
  float4 o0=a0p[0], o1=a0p[1];
  o0.x+=s[0]; o0.y+=s[1]; o0.z+=s[2]; o0.w+=s[3];
  o1.x+=s[4]; o1.y+=s[5]; o1.z+=s[6]; o1.w+=s[7];
  a0p[0]=o0; a0p[1]=o1;
}

// ---------------- node-wise symmetric tensor product (product basis) ----------------
__global__ __launch_bounds__(256) void k_tp_node(
    const float* __restrict__ in, float* __restrict__ out,
    const float* __restrict__ pb, const int* __restrict__ z, int N)
{
  int t=blockIdx.x*256+threadIdx.x;
  int n=t>>5, f=t&31;
  if(n>=N) return;
  float A[16];
  {
    const float4* p=(const float4*)(in+(size_t)n*512+f*16);
    float4 a=p[0],b=p[1],c=p[2],d=p[3];
    A[0]=a.x; A[1]=a.y; A[2]=a.z; A[3]=a.w;
    A[4]=b.x; A[5]=b.y; A[6]=b.z; A[7]=b.w;
    A[8]=c.x; A[9]=c.y; A[10]=c.z; A[11]=c.w;
    A[12]=d.x; A[13]=d.y; A[14]=d.z; A[15]=d.w;
  }
  float B2[16]; float B3[16];
  #pragma unroll
  for(int c=0;c<16;c++){ B2[c]=0.f; B3[c]=0.f; }
  tpn_paths<0>(A,A,B2);
  tpn_paths<0>(B2,A,B3);
  int zz=z[n];
  float wa=pb[zz*96+f], wb=pb[zz*96+32+f], wc=pb[zz*96+64+f];
  float o[16];
  #pragma unroll
  for(int c=0;c<16;c++) o[c]=wa*A[c]+wb*B2[c]+wc*B3[c];
  float4* op=(float4*)(out+(size_t)n*512+f*16);
  op[0]=make_float4(o[0],o[1],o[2],o[3]);
  op[1]=make_float4(o[4],o[5],o[6],o[7]);
  op[2]=make_float4(o[8],o[9],o[10],o[11]);
  op[3]=make_float4(o[12],o[13],o[14],o[15]);
}

// ---------------- merged readout: e0 dot + residual matmul ----------------
__global__ __launch_bounds__(256) void k_readout(
    const float* __restrict__ feats, const float* __restrict__ ro0,
    const float* __restrict__ res1, const int* __restrict__ z,
    float* __restrict__ e0, float* __restrict__ resid, int N)
{
  int t=blockIdx.x*256+threadIdx.x;
  int n=t>>5, g=t&31;
  if(n>=N) return;
  const float* wp=res1+(size_t)z[n]*1024;
  float a=0.f;
  #pragma unroll 8
  for(int f=0;f<32;f++) a=fmaf(feats[(size_t)n*512+f*16], wp[(f<<5)+g], a);
  resid[(size_t)n*32+g]=a;
  if(g==0){
    float b=0.f;
    #pragma unroll 8
    for(int f=0;f<32;f++) b=fmaf(feats[(size_t)n*512+f*16], ro0[f], b);
    e0[n]=b;
  }
}

__global__ __launch_bounds__(256) void k_final(
    const float* __restrict__ h, const float* __restrict__ resid,
    const float* __restrict__ e0a, const float* __restrict__ ro1a,
    const float* __restrict__ ro1b, float* __restrict__ out, int N)
{
  int t=blockIdx.x*256+threadIdx.x;
  float val=0.f;
  if (t<N){
    float sc[32];
    #pragma unroll 8
    for(int f=0;f<32;f++) sc[f]=h[(size_t)t*512+f*16]+resid[(size_t)t*32+f];
    float e1=0.f;
    #pragma unroll
    for(int j=0;j<16;j++){
      float a=0.f;
      #pragma unroll
      for(int f=0;f<32;f++) a=fmaf(sc[f],ro1a[f*16+j],a);
      float s=a/(1.f+__expf(-a));
      e1=fmaf(s,ro1b[j],e1);
    }
    val = -1.5f + 2.0f*(e0a[t]+e1) - 10.0f;
  }
  __shared__ float red[256];
  red[threadIdx.x]=val;
  __syncthreads();
  for(int s=128;s>0;s>>=1){
    if(threadIdx.x<s) red[threadIdx.x]+=red[threadIdx.x+s];
    __syncthreads();
  }
  if(threadIdx.x==0) atomicAdd(out, red[0]);
}

// ---------------- host orchestration ----------------
extern "C" void kernel_launch(void* const* d_in, const int* in_sizes, int n_in,
                              void* d_out, int out_size, void* d_ws, size_t ws_size,
                              hipStream_t stream)
{
  const float* vec   =(const float*)d_in[0];
  const int*   zarr  =(const int*)  d_in[1];
  const int*   snd   =(const int*)  d_in[2];
  const int*   rcv   =(const int*)  d_in[3];
  const float* embed =(const float*)d_in[4];
  const float* r0w0  =(const float*)d_in[5];
  const float* r0w1  =(const float*)d_in[6];
  const float* r0w2  =(const float*)d_in[7];
  const float* up0   =(const float*)d_in[8];
  const float* post0 =(const float*)d_in[9];
  const float* pb0   =(const float*)d_in[10];
  const float* pblin0=(const float*)d_in[11];
  const float* r1w0  =(const float*)d_in[12];
  const float* r1w1  =(const float*)d_in[13];
  const float* r1w2  =(const float*)d_in[14];
  const float* up1   =(const float*)d_in[15];
  const float* post1 =(const float*)d_in[16];
  const float* pb1   =(const float*)d_in[17];
  const float* pblin1=(const float*)d_in[18];
  const float* sel0  =(const float*)d_in[19];
  const float* ro0   =(const float*)d_in[20];
  const float* res1  =(const float*)d_in[21];
  const float* ro1a  =(const float*)d_in[22];
  const float* ro1b  =(const float*)d_in[23];

  const int E = in_sizes[0]/3;
  const int N = in_sizes[1];
  const int Epad = (E+63)&~63;

  char* ws=(char*)d_ws;
  size_t o=0;
  auto alloc=[&](size_t bytes)->char*{
    char* p=ws+o;
    o=(o+bytes+255)&~(size_t)255;
    return p;
  };
  int*   deg  =(int*)  alloc((size_t)N*4);
  int*   rowp =(int*)  alloc((size_t)(N+1)*4);
  int*   cur  =(int*)  alloc((size_t)N*4);
  int*   eid  =(int*)  alloc((size_t)E*4);
  int*   snd_s=(int*)  alloc((size_t)E*4);
  float* Yb   =(float*)alloc((size_t)E*16*4);
  float* radb =(float*)alloc((size_t)E*8*4);
  unsigned short* hidb=(unsigned short*)alloc((size_t)(Epad+16)*64*2);
  unsigned short* w2t0=(unsigned short*)alloc((size_t)1088*64*2);
  unsigned short* w2t1=(unsigned short*)alloc((size_t)1088*64*2);
  unsigned short* hl16=(unsigned short*)alloc((size_t)N*512*2);
  float* feats=(float*)alloc((size_t)N*512*4);
  float* bufA =(float*)alloc((size_t)N*512*4);
  float* bufB =(float*)alloc((size_t)N*512*4);
  float* bufC =(float*)alloc((size_t)N*512*4);
  float* e0b  =(float*)alloc((size_t)N*4);
  float* residb=(float*)alloc((size_t)N*32*4);
  char*  dyn  = ws+o;
  size_t remain = ws_size>o ? ws_size-o : 0;

  dim3 tb(256);
  dim3 nblk((unsigned)((N*32+255)/256));
  dim3 eblk((unsigned)((E+255)/256));
  dim3 qblk((unsigned)((N*64+255)/256));

  // CSR build (receiver-sorted edge order)
  hipMemsetAsync(deg,0,(size_t)N*4,stream);
  k_count<<<eblk,tb,0,stream>>>(rcv,deg,E);
  k_scan<<<dim3(1),dim3(1024),0,stream>>>(deg,rowp,cur,N);
  k_fill<<<eblk,tb,0,stream>>>(rcv,cur,eid,E);

  k_edge_setup<<<eblk,tb,0,stream>>>(vec,snd,eid,Yb,radb,snd_s,E);
  k_node_init<<<nblk,tb,0,stream>>>(embed,zarr,feats,N);

  // cast+transpose radial-MLP final weights to bf16 (per launch)
  k_cast2<<<dim3((2*1088*64+255)/256),tb,0,stream>>>(r0w2,r1w2,w2t0,w2t1);

  auto run_edges=[&](bool l0, const unsigned short* hlin, const unsigned short* w2t, float* agg){
    // per-edge workspace: msgs only (rw lives in LDS inside the fused kernel)
    long rows = (long)(remain/1024);
    rows -= rows%64;
    if (rows>(long)Epad) rows=Epad;
    if (rows<64) rows=64;
    unsigned short* msgsb = (unsigned short*)dyn;
    for(long eb=0;eb<E;eb+=rows){
      long cnt = E-eb; if(cnt>rows) cnt=rows;
      dim3 g2((unsigned)((cnt+15)/16));
      if(l0) k_tp_fused<true ><<<g2,tb,0,stream>>>(hlin,Yb,hidb+(size_t)eb*64,w2t,snd_s,msgsb,(int)eb,(int)cnt);
      else   k_tp_fused<false><<<g2,tb,0,stream>>>(hlin,Yb,hidb+(size_t)eb*64,w2t,snd_s,msgsb,(int)eb,(int)cnt);
      k_seg_sum<<<qblk,tb,0,stream>>>(msgsb,rowp,agg,(int)eb,(int)cnt,N);
    }
  };

  // ---- layer 0 ----
  k_lin16<<<nblk,tb,0,stream>>>(feats,hl16,up0,N);
  k_radial<<<eblk,tb,0,stream>>>(radb,r0w0,r0w1,hidb,E);
  hipMemsetAsync(bufB,0,(size_t)N*512*4,stream);
  run_edges(true,hl16,w2t0,bufB);
  k_lin<<<nblk,tb,0,stream>>>(bufB,bufC,post0,(const int*)nullptr,0,N);
  k_lin<<<nblk,tb,0,stream>>>(bufC,bufA,sel0,zarr,4096,N);
  k_tp_node<<<nblk,tb,0,stream>>>(bufA,bufB,pb0,zarr,N);
  k_lin<<<nblk,tb,0,stream>>>(bufB,feats,pblin0,(const int*)nullptr,0,N);
  k_readout<<<nblk,tb,0,stream>>>(feats,ro0,res1,zarr,e0b,residb,N);

  // ---- layer 1 ----
  k_lin16<<<nblk,tb,0,stream>>>(feats,hl16,up1,N);
  k_radial<<<eblk,tb,0,stream>>>(radb,r1w0,r1w1,hidb,E);
  hipMemsetAsync(bufC,0,(size_t)N*512*4,stream);
  run_edges(false,hl16,w2t1,bufC);
  k_lin<<<nblk,tb,0,stream>>>(bufC,bufB,post1,(const int*)nullptr,0,N);
  k_tp_node<<<nblk,tb,0,stream>>>(bufB,bufA,pb1,zarr,N);
  k_lin<<<nblk,tb,0,stream>>>(bufA,bufC,pblin1,(const int*)nullptr,0,N);

  hipMemsetAsync(d_out,0,4,stream);
  k_final<<<dim3((N+255)/256),tb,0,stream>>>(bufC,residb,e0b,ro1a,ro1b,(float*)d_out,N);
}

// Round 13
// 893.423 us; speedup vs baseline: 2.6297x; 1.1549x over previous
//
#include <hip/hip_runtime.h>
#include <math.h>

// ---------------- static config ----------------
#define NF 32
#define NPATHS 34

typedef __attribute__((ext_vector_type(8))) short bf16x8;
typedef __attribute__((ext_vector_type(4))) float f32x4;

__device__ __forceinline__ unsigned short f2bf(float v){
  unsigned u = __float_as_uint(v);
  u += 0x7fffu + ((u>>16)&1u);
  return (unsigned short)(u>>16);
}
__device__ __forceinline__ float bf2f(unsigned short h){
  return __uint_as_float(((unsigned)h)<<16);
}

struct PathTab { int l1[NPATHS]; int l2[NPATHS]; int l3[NPATHS]; };
constexpr PathTab mkpaths(){
  PathTab t{}; int n=0;
  for(int a=0;a<=3;a++)for(int b=0;b<=3;b++)for(int c=0;c<=3;c++){
    int lo = a>b ? a-b : b-a;
    if(c>=lo && c<=a+b){ t.l1[n]=a; t.l2[n]=b; t.l3[n]=c; n++; }
  }
  return t;
}
constexpr PathTab PT = mkpaths();

// ---------------- compile-time Wigner-3j (exact replica of reference math) ----------------
struct FactT { double v[22]; };
constexpr FactT mkfactT(){ FactT f{}; f.v[0]=1.0; for(int i=1;i<22;i++) f.v[i]=f.v[i-1]*(double)i; return f; }
constexpr FactT FT = mkfactT();
constexpr double cfact(int n){ return FT.v[n]; }

constexpr double csqrt(double x){
  if(x<=0.0) return 0.0;
  double g = x<1.0 ? 1.0 : x;
  for(int i=0;i<40;i++) g=0.5*(g+x/g);
  return g;
}

constexpr double su2cg(int j1,int j2,int j3,int m1,int m2){
  int m3=m1+m2;
  if(m3<-j3||m3>j3) return 0.0;
  double pref = (double)(2*j3+1)*cfact(j3+j1-j2)*cfact(j3-j1+j2)*cfact(j1+j2-j3)/cfact(j1+j2+j3+1);
  pref *= cfact(j3+m3)*cfact(j3-m3)*cfact(j1-m1)*cfact(j1+m1)*cfact(j2-m2)*cfact(j2+m2);
  pref = csqrt(pref);
  int k0=0; if(j2-j3-m1>k0)k0=j2-j3-m1; if(j1-j3+m2>k0)k0=j1-j3+m2;
  int k1=j1+j2-j3; if(j1-m1<k1)k1=j1-m1; if(j2+m2<k1)k1=j2+m2;
  double s=0.0;
  for(int k=k0;k<=k1;k++){
    double d = cfact(k)*cfact(j1+j2-j3-k)*cfact(j1-m1-k)*cfact(j2+m2-k)*cfact(j3-j2+m1+k)*cfact(j3-j1-m2+k);
    s += (k&1)? -1.0/d : 1.0/d;
  }
  return pref*s;
}

struct ccd { double x, y; };
constexpr ccd cqval(int l,int r,int col){
  const double is2 = 0.70710678118654752440;
  double re=0.0, im=0.0;
  if (r<l){ if (col==2*l-r) re=is2; else if (col==r) im=-is2; }
  else if (r==l){ if (col==l) re=1.0; }
  else { double s = ((r-l)&1)? -1.0:1.0;
         if (col==r) re=s*is2; else if (col==2*l-r) im=s*is2; }
  ccd v{re,im};
  switch(l&3){           // multiply by (-i)^l
    case 1: return ccd{ v.y, -v.x };
    case 2: return ccd{-v.x, -v.y };
    case 3: return ccd{-v.y,  v.x };
    default: return v;
  }
}

constexpr double w3entry(int l1,int l2,int l3,int i,int j,int k){
  double re=0.0;
  for(int a=0;a<2*l1+1;a++){
    ccd qa=cqval(l1,a,i); if(qa.x==0.0&&qa.y==0.0) continue;
    for(int b=0;b<2*l2+1;b++){
      ccd qb=cqval(l2,b,j); if(qb.x==0.0&&qb.y==0.0) continue;
      int m1=a-l1, m2=b-l2, m3=m1+m2;
      if(m3<-l3||m3>l3) continue;
      int c=m3+l3;
      double cg=su2cg(l1,l2,l3,m1,m2); if(cg==0.0) continue;
      ccd qc=cqval(l3,c,k); qc.y=-qc.y;   // conj
      if(qc.x==0.0&&qc.y==0.0) continue;
      ccd ab{qa.x*qb.x-qa.y*qb.y, qa.x*qb.y+qa.y*qb.x};
      re += cg*(ab.x*qc.x - ab.y*qc.y);
    }
  }
  return re;
}

template<int L1,int L2,int L3> struct W3Arr { float v[(2*L1+1)*(2*L2+1)*(2*L3+1)]; };
template<int L1,int L2,int L3> constexpr W3Arr<L1,L2,L3> mkW3(double scale){
  W3Arr<L1,L2,L3> r{};
  for(int i=0;i<2*L1+1;i++)
    for(int j=0;j<2*L2+1;j++)
      for(int k=0;k<2*L3+1;k++)
        r.v[(i*(2*L2+1)+j)*(2*L3+1)+k] = (float)(w3entry(L1,L2,L3,i,j,k)*scale);
  return r;
}
template<int L1,int L2,int L3> constexpr W3Arr<L1,L2,L3> W3V = mkW3<L1,L2,L3>(1.0);
template<int L1,int L2,int L3> constexpr W3Arr<L1,L2,L3> W3N = mkW3<L1,L2,L3>(1.0/csqrt(2.0*L3+1.0));

// SH recursion scales (replica of reference _sh_scales, float64 like numpy)
struct SCt { double sc2, sc3; };
constexpr SCt mksc(){
  double v0=0.2,v1=-0.6,v2=0.7;
  double nv=csqrt(v0*v0+v1*v1+v2*v2);
  double s3=csqrt(3.0);
  double y1[3]={s3*v0/nv, s3*v1/nv, s3*v2/nv};
  double t2[5]={0,0,0,0,0}; double n2=0.0;
  for(int c=0;c<5;c++){
    double s=0.0;
    for(int a=0;a<3;a++)for(int b=0;b<3;b++) s += w3entry(1,1,2,a,b,c)*y1[a]*y1[b];
    t2[c]=s; n2+=s*s;
  }
  double sc2=csqrt(5.0)/csqrt(n2);
  double y2[5]={sc2*t2[0],sc2*t2[1],sc2*t2[2],sc2*t2[3],sc2*t2[4]};
  double n3=0.0;
  for(int c=0;c<7;c++){
    double s=0.0;
    for(int a=0;a<5;a++)for(int b=0;b<3;b++) s += w3entry(2,1,3,a,b,c)*y2[a]*y1[b];
    n3+=s*s;
  }
  double sc3=csqrt(7.0)/csqrt(n3);
  return SCt{sc2,sc3};
}
constexpr SCt SCV = mksc();

// ---------------- template-unrolled TP with literal W3J, true-zero elision ----------------
// direct form: acc[l3^2+C] += w * x*y * rv   (used for node TP / SH setup)
template<bool NORM,int l1,int l2,int l3,int A,int B,int C>
__device__ __forceinline__ void w3term(const float* __restrict__ x, const float* __restrict__ y,
                                       float rv, float* __restrict__ acc){
  constexpr float w = NORM ? W3N<l1,l2,l3>.v[(A*(2*l2+1)+B)*(2*l3+1)+C]
                           : W3V<l1,l2,l3>.v[(A*(2*l2+1)+B)*(2*l3+1)+C];
  if constexpr (w!=0.0f)
    acc[l3*l3+C] = fmaf(w, x[l1*l1+A]*y[l2*l2+B]*rv, acc[l3*l3+C]);
}
template<bool NORM,int l1,int l2,int l3,int A,int B,int C>
__device__ __forceinline__ void w3loopC(const float* x,const float* y,float rv,float* acc){
  if constexpr (C<2*l3+1){
    w3term<NORM,l1,l2,l3,A,B,C>(x,y,rv,acc);
    w3loopC<NORM,l1,l2,l3,A,B,C+1>(x,y,rv,acc);
  }
}
template<bool NORM,int l1,int l2,int l3,int A,int B>
__device__ __forceinline__ void w3loopB(const float* x,const float* y,float rv,float* acc){
  if constexpr (B<2*l2+1){
    w3loopC<NORM,l1,l2,l3,A,B,0>(x,y,rv,acc);
    w3loopB<NORM,l1,l2,l3,A,B+1>(x,y,rv,acc);
  }
}
template<bool NORM,int l1,int l2,int l3,int A>
__device__ __forceinline__ void w3loopA(const float* x,const float* y,float rv,float* acc){
  if constexpr (A<2*l1+1){
    w3loopB<NORM,l1,l2,l3,A,0>(x,y,rv,acc);
    w3loopA<NORM,l1,l2,l3,A+1>(x,y,rv,acc);
  }
}

// factored form: S[C] += w * (x*y); rv applied once per output (edge TP hot loop)
template<int l1,int l2,int l3,int A,int B,int C>
__device__ __forceinline__ void w3termS(const float* __restrict__ x, const float* __restrict__ y,
                                        float* __restrict__ S){
  constexpr float w = W3V<l1,l2,l3>.v[(A*(2*l2+1)+B)*(2*l3+1)+C];
  if constexpr (w!=0.0f)
    S[C] = fmaf(w, x[l1*l1+A]*y[l2*l2+B], S[C]);
}
template<int l1,int l2,int l3,int A,int B,int C>
__device__ __forceinline__ void w3loopSC(const float* x,const float* y,float* S){
  if constexpr (C<2*l3+1){
    w3termS<l1,l2,l3,A,B,C>(x,y,S);
    w3loopSC<l1,l2,l3,A,B,C+1>(x,y,S);
  }
}
template<int l1,int l2,int l3,int A,int B>
__device__ __forceinline__ void w3loopSB(const float* x,const float* y,float* S){
  if constexpr (B<2*l2+1){
    w3loopSC<l1,l2,l3,A,B,0>(x,y,S);
    w3loopSB<l1,l2,l3,A,B+1>(x,y,S);
  }
}
template<int l1,int l2,int l3,int A>
__device__ __forceinline__ void w3loopSA(const float* x,const float* y,float* S){
  if constexpr (A<2*l1+1){
    w3loopSB<l1,l2,l3,A,0>(x,y,S);
    w3loopSA<l1,l2,l3,A+1>(x,y,S);
  }
}

template<bool L0,int P>
__device__ __forceinline__ void tp_paths(const float* hs,const float* yv,
                                         const unsigned short* rp, float* acc){
  if constexpr (P<NPATHS){
    constexpr int l1=PT.l1[P], l2=PT.l2[P], l3=PT.l3[P];
    if constexpr (!(L0 && l1!=0)){
      float S[2*l3+1];
      #pragma unroll
      for(int c=0;c<2*l3+1;c++) S[c]=0.f;
      w3loopSA<l1,l2,l3,0>(hs,yv,S);
      float rv = bf2f(rp[P*32]);
      #pragma unroll
      for(int c=0;c<2*l3+1;c++) acc[l3*l3+c]=fmaf(rv,S[c],acc[l3*l3+c]);
    }
    tp_paths<L0,P+1>(hs,yv,rp,acc);
  }
}

template<int P>
__device__ __forceinline__ void tpn_paths(const float* x,const float* y,float* o){
  if constexpr (P<NPATHS){
    constexpr int l1=PT.l1[P], l2=PT.l2[P], l3=PT.l3[P];
    w3loopA<true,l1,l2,l3,0>(x,y,1.0f,o);
    tpn_paths<P+1>(x,y,o);
  }
}

// scalar-only node TP: l3=0 paths (l,l,0) only
__device__ __forceinline__ float tpn_scalar(const float* x,const float* y){
  float o[1]={0.f};
  w3loopA<true,0,0,0,0>(x,y,1.0f,o);
  w3loopA<true,1,1,0,0>(x,y,1.0f,o);
  w3loopA<true,2,2,0,0>(x,y,1.0f,o);
  w3loopA<true,3,3,0,0>(x,y,1.0f,o);
  return o[0];
}

// ---------------- CSR build: degree count, scan, fill ----------------
__global__ __launch_bounds__(256) void k_count(
    const int* __restrict__ rcv, int* __restrict__ deg, int E)
{
  int e=blockIdx.x*256+threadIdx.x;
  if(e>=E) return;
  atomicAdd(&deg[rcv[e]],1);
}

#define SCAN_PER 32
__global__ __launch_bounds__(1024) void k_scan(
    const int* __restrict__ deg, int* __restrict__ row,
    int* __restrict__ cur, int N)
{
  __shared__ int part[1024];
  int t=threadIdx.x;
  int per=(N+1023)/1024; if(per>SCAN_PER) per=SCAN_PER;
  int base=t*per;
  int loc[SCAN_PER];
  int s=0;
  for(int i=0;i<per;i++){ int idx=base+i; int v=(idx<N)? deg[idx]:0; loc[i]=s; s+=v; }
  part[t]=s;
  __syncthreads();
  for(int off=1;off<1024;off<<=1){
    int v=(t>=off)? part[t-off]:0;
    __syncthreads();
    part[t]+=v;
    __syncthreads();
  }
  int ex=(t==0)?0:part[t-1];
  for(int i=0;i<per;i++){
    int idx=base+i;
    if(idx<N){ int r=ex+loc[i]; row[idx]=r; cur[idx]=r; }
  }
  if(t==1023) row[N]=part[1023];
}

__global__ __launch_bounds__(256) void k_fill(
    const int* __restrict__ rcv, int* __restrict__ cur,
    int* __restrict__ eid, int E)
{
  int e=blockIdx.x*256+threadIdx.x;
  if(e>=E) return;
  int pos=atomicAdd(&cur[rcv[e]],1);
  eid[pos]=e;
}

// ---------------- per-edge geometry (receiver-sorted order): SH + radial basis ----------------
__global__ __launch_bounds__(256) void k_edge_setup(
    const float* __restrict__ vec, const int* __restrict__ snd,
    const int* __restrict__ eid, float* __restrict__ Y,
    float* __restrict__ rad, int* __restrict__ snd_s, int E)
{
  int j = blockIdx.x*256+threadIdx.x;
  if (j>=E) return;
  int e = eid[j];
  snd_s[j]=snd[e];
  float vx=vec[3*e], vy=vec[3*e+1], vz=vec[3*e+2];
  float r=sqrtf(vx*vx+vy*vy+vz*vz);
  float inv=1.0f/fmaxf(r,1e-9f);
  float y[16];
  y[0]=1.0f;
  const float s3=1.7320508075688772f;
  y[1]=s3*vx*inv; y[2]=s3*vy*inv; y[3]=s3*vz*inv;
  constexpr float sc2=(float)SCV.sc2, sc3=(float)SCV.sc3;
  {
    float t[16];
    #pragma unroll
    for(int c=0;c<16;c++) t[c]=0.f;
    w3loopA<false,1,1,2,0>(y,y,1.0f,t);     // t[4..8] = einsum(w112, y1, y1)
    #pragma unroll
    for(int c=0;c<5;c++) y[4+c]=sc2*t[4+c];
    w3loopA<false,2,1,3,0>(y,y,1.0f,t);     // t[9..15] = einsum(w213, y2, y1)
    #pragma unroll
    for(int c=0;c<7;c++) y[9+c]=sc3*t[9+c];
  }
  float4* Yp=(float4*)(Y+(size_t)j*16);
  Yp[0]=make_float4(y[0],y[1],y[2],y[3]);
  Yp[1]=make_float4(y[4],y[5],y[6],y[7]);
  Yp[2]=make_float4(y[8],y[9],y[10],y[11]);
  Yp[3]=make_float4(y[12],y[13],y[14],y[15]);
  float x = r*0.2f;
  float env=0.f;
  if (x<1.0f){
    float x2=x*x; float x4=x2*x2; float x5=x4*x;
    env = 1.0f - 21.0f*x5 + 35.0f*x5*x - 15.0f*x5*x2;
  }
  const float cb = 0.632455532033675866f; // sqrt(2/5)
  float base = inv*env*cb;
  #pragma unroll
  for(int n=1;n<=8;n++)
    rad[(size_t)j*8 + n-1] = base*sinf(3.14159265358979323846f * x * (float)n);
}

// ---------------- node init: scalar embedding ----------------
__global__ __launch_bounds__(256) void k_node_init(
    const float* __restrict__ embed, const int* __restrict__ z,
    float* __restrict__ feats, int N)
{
  int t = blockIdx.x*256+threadIdx.x;
  int n=t>>5, f=t&31;
  if(n>=N) return;
  float v = embed[z[n]*NF + f];
  float4* p=(float4*)(feats + (size_t)n*512 + f*16);
  p[0]=make_float4(v,0.f,0.f,0.f);
  p[1]=make_float4(0.f,0.f,0.f,0.f);
  p[2]=make_float4(0.f,0.f,0.f,0.f);
  p[3]=make_float4(0.f,0.f,0.f,0.f);
}

// ---------------- per-l channel-mixing linear (f32 out) ----------------
__global__ __launch_bounds__(256) void k_lin(
    const float* __restrict__ in, float* __restrict__ out,
    const float* __restrict__ w, const int* __restrict__ z, int zstride, int N)
{
  int t=blockIdx.x*256+threadIdx.x;
  int n=t>>5, g=t&31;
  if(n>=N) return;
  const float* wp = w + (z ? (size_t)z[n]*(size_t)zstride : 0);
  const float* ip = in + (size_t)n*512;
  float acc[16];
  #pragma unroll
  for(int c=0;c<16;c++) acc[c]=0.f;
  #pragma unroll 8
  for(int f=0; f<NF; f++){
    const float4* xp = (const float4*)(ip + f*16);
    float4 x0=xp[0], x1=xp[1], x2=xp[2], x3=xp[3];
    float w0v=wp[(f<<5)+g], w1v=wp[1024+(f<<5)+g], w2v=wp[2048+(f<<5)+g], w3v=wp[3072+(f<<5)+g];
    acc[0]  = fmaf(x0.x,w0v,acc[0]);
    acc[1]  = fmaf(x0.y,w1v,acc[1]);
    acc[2]  = fmaf(x0.z,w1v,acc[2]);
    acc[3]  = fmaf(x0.w,w1v,acc[3]);
    acc[4]  = fmaf(x1.x,w2v,acc[4]);
    acc[5]  = fmaf(x1.y,w2v,acc[5]);
    acc[6]  = fmaf(x1.z,w2v,acc[6]);
    acc[7]  = fmaf(x1.w,w2v,acc[7]);
    acc[8]  = fmaf(x2.x,w2v,acc[8]);
    acc[9]  = fmaf(x2.y,w3v,acc[9]);
    acc[10] = fmaf(x2.z,w3v,acc[10]);
    acc[11] = fmaf(x2.w,w3v,acc[11]);
    acc[12] = fmaf(x3.x,w3v,acc[12]);
    acc[13] = fmaf(x3.y,w3v,acc[13]);
    acc[14] = fmaf(x3.z,w3v,acc[14]);
    acc[15] = fmaf(x3.w,w3v,acc[15]);
  }
  float4* op=(float4*)(out + (size_t)n*512 + g*16);
  op[0]=make_float4(acc[0],acc[1],acc[2],acc[3]);
  op[1]=make_float4(acc[4],acc[5],acc[6],acc[7]);
  op[2]=make_float4(acc[8],acc[9],acc[10],acc[11]);
  op[3]=make_float4(acc[12],acc[13],acc[14],acc[15]);
}

// ---------------- per-l channel-mixing linear (bf16 out, for fused-TP input) ----------------
__global__ __launch_bounds__(256) void k_lin16(
    const float* __restrict__ in, unsigned short* __restrict__ out,
    const float* __restrict__ w, int N)
{
  int t=blockIdx.x*256+threadIdx.x;
  int n=t>>5, g=t&31;
  if(n>=N) return;
  const float* wp = w;
  const float* ip = in + (size_t)n*512;
  float acc[16];
  #pragma unroll
  for(int c=0;c<16;c++) acc[c]=0.f;
  #pragma unroll 8
  for(int f=0; f<NF; f++){
    const float4* xp = (const float4*)(ip + f*16);
    float4 x0=xp[0], x1=xp[1], x2=xp[2], x3=xp[3];
    float w0v=wp[(f<<5)+g], w1v=wp[1024+(f<<5)+g], w2v=wp[2048+(f<<5)+g], w3v=wp[3072+(f<<5)+g];
    acc[0]  = fmaf(x0.x,w0v,acc[0]);
    acc[1]  = fmaf(x0.y,w1v,acc[1]);
    acc[2]  = fmaf(x0.z,w1v,acc[2]);
    acc[3]  = fmaf(x0.w,w1v,acc[3]);
    acc[4]  = fmaf(x1.x,w2v,acc[4]);
    acc[5]  = fmaf(x1.y,w2v,acc[5]);
    acc[6]  = fmaf(x1.z,w2v,acc[6]);
    acc[7]  = fmaf(x1.w,w2v,acc[7]);
    acc[8]  = fmaf(x2.x,w2v,acc[8]);
    acc[9]  = fmaf(x2.y,w3v,acc[9]);
    acc[10] = fmaf(x2.z,w3v,acc[10]);
    acc[11] = fmaf(x2.w,w3v,acc[11]);
    acc[12] = fmaf(x3.x,w3v,acc[12]);
    acc[13] = fmaf(x3.y,w3v,acc[13]);
    acc[14] = fmaf(x3.z,w3v,acc[14]);
    acc[15] = fmaf(x3.w,w3v,acc[15]);
  }
  bf16x8 o0,o1;
  #pragma unroll
  for(int c=0;c<8;c++){ o0[c]=(short)f2bf(acc[c]); o1[c]=(short)f2bf(acc[8+c]); }
  bf16x8* op=(bf16x8*)(out + (size_t)n*512 + g*16);
  op[0]=o0; op[1]=o1;
}

// ---------------- scalar-only linear: in [N,32] packed -> out [N,32] packed ----------------
__global__ __launch_bounds__(256) void k_lin_sc(
    const float* __restrict__ in, float* __restrict__ out,
    const float* __restrict__ w, int N)
{
  int t=blockIdx.x*256+threadIdx.x;
  int n=t>>5, g=t&31;
  if(n>=N) return;
  const float* ip=in+(size_t)n*32;
  float a=0.f;
  #pragma unroll 8
  for(int f=0;f<32;f++) a=fmaf(ip[f], w[(f<<5)+g], a);
  out[(size_t)n*32+g]=a;
}

// ---------------- combine post0 @ sel0 per species: comb[z,l] = post0[l] x sel0[z,l] ----------------
__global__ __launch_bounds__(256) void k_wcomb(
    const float* __restrict__ post0, const float* __restrict__ sel0,
    float* __restrict__ comb)
{
  int t=blockIdx.x*256+threadIdx.x;
  if(t>=10*4096) return;
  int z=t>>12, r=t&4095;
  int l=r>>10, e=(r>>5)&31, g=r&31;
  const float* pp=post0+l*1024+e*32;
  const float* sp=sel0+(size_t)z*4096+l*1024;
  float a=0.f;
  #pragma unroll 8
  for(int f=0;f<32;f++) a=fmaf(pp[f], sp[f*32+g], a);
  comb[(size_t)z*4096 + l*1024 + e*32 + g]=a;
}

// ---------------- radial MLP hidden layers (bf16 output) ----------------
__global__ __launch_bounds__(256) void k_radial(
    const float* __restrict__ rad, const float* __restrict__ w0,
    const float* __restrict__ w1, unsigned short* __restrict__ hid, int E)
{
  __shared__ float w0s[8*64];
  __shared__ float w1s[64*64];
  int tid=threadIdx.x;
  for(int i=tid;i<512;i+=256) w0s[i]=w0[i];
  for(int i=tid;i<4096;i+=256) w1s[i]=w1[i];
  __syncthreads();
  int e=blockIdx.x*256+tid;
  if(e>=E) return;
  const float4* rp=(const float4*)(rad+(size_t)e*8);
  float4 ra=rp[0], rb=rp[1];
  float rv[8]={ra.x,ra.y,ra.z,ra.w,rb.x,rb.y,rb.z,rb.w};
  float h1[64];
  #pragma unroll 8
  for(int j=0;j<64;j++){
    float a=0.f;
    #pragma unroll
    for(int i=0;i<8;i++) a=fmaf(rv[i],w0s[i*64+j],a);
    h1[j]=a/(1.f+__expf(-a));
  }
  unsigned short* hp = hid+(size_t)e*64;
  #pragma unroll 4
  for(int j=0;j<64;j++){
    float a=0.f;
    #pragma unroll
    for(int i=0;i<64;i++) a=fmaf(h1[i],w1s[i*64+j],a);
    hp[j]=f2bf(a/(1.f+__expf(-a)));
  }
}

// ---------------- cast+transpose both w2 [64 x 1088] -> w2t [1088 x 64] bf16 ----------------
__global__ __launch_bounds__(256) void k_cast2(
    const float* __restrict__ w2a, const float* __restrict__ w2b,
    unsigned short* __restrict__ ta, unsigned short* __restrict__ tb)
{
  int t=blockIdx.x*256+threadIdx.x;
  if(t>=2*1088*64) return;
  const float* src = (t<1088*64)? w2a : w2b;
  unsigned short* dst = (t<1088*64)? ta : tb;
  int u = (t<1088*64)? t : t-1088*64;
  int c=u>>6, k=u&63;
  dst[(size_t)c*64+k]=f2bf(src[(size_t)k*1088+c]);
}

// ---------------- FUSED: MFMA rw-GEMM (to LDS) + edge tensor product -> messages ----------------
// Block = 16 edges. Phase 1: rw[16 x RWLD] = hid[16x64] @ w2t^T via 16x16x32 MFMA,
// D -> LDS [edge][col] (col = p*32+f). LSTR ≡ 4 mod 16: 0 bank conflicts (measured R10/R12).
// snd_s hoisted before phase 1. NO launch_bounds min-waves (R11: forced VGPR=64 spilled 6.8GB).
// MFMA layouts (HW-verified m89/m120): A-frag A[m=lane&15][k=quad*8+j];
// B-frag B[k=quad*8+j][n=lane&15]; D: row=quad*4+reg, col=lane&15.
template<bool L0>
__global__ __launch_bounds__(256) void k_tp_fused(
    const unsigned short* __restrict__ hlin, const float* __restrict__ Y,
    const unsigned short* __restrict__ hid, const unsigned short* __restrict__ w2t,
    const int* __restrict__ snd_s, unsigned short* __restrict__ msgs,
    int eb, int ecnt)
{
  constexpr int RWLD = L0 ? 128 : 1088;
  constexpr int LSTR = L0 ? 132 : 1092;
  __shared__ unsigned short rws[16*LSTR];
  int tid=threadIdx.x;
  int lane=tid&63, wave=tid>>6;
  int m16=lane&15, quad=lane>>4;
  int el0=blockIdx.x*16;
  int f=tid&31;
  int w=tid>>6, hb=(tid>>5)&1;
  int le_base = w + hb*8;
  int el_s0 = el0 + le_base;
  int el_s1 = el0 + le_base + 4;
  int s0 = (el_s0<ecnt)? snd_s[eb+el_s0] : 0;
  int s1 = (el_s1<ecnt)? snd_s[eb+el_s1] : 0;
  // ---- phase 1: rw tile via MFMA, D -> LDS ----
  {
    const unsigned short* Ab = hid + (size_t)el0*64;   // hid already offset by eb
    bf16x8 a0 = *(const bf16x8*)(Ab + m16*64 + quad*8);
    bf16x8 a1 = *(const bf16x8*)(Ab + m16*64 + 32 + quad*8);
    #pragma unroll 2
    for(int nt=wave; nt<RWLD/16; nt+=4){
      int col = nt*16 + m16;
      bf16x8 b0 = *(const bf16x8*)(w2t + (size_t)col*64 + quad*8);
      bf16x8 b1 = *(const bf16x8*)(w2t + (size_t)col*64 + 32 + quad*8);
      f32x4 acc = (f32x4){0.f,0.f,0.f,0.f};
      acc = __builtin_amdgcn_mfma_f32_16x16x32_bf16(a0,b0,acc,0,0,0);
      acc = __builtin_amdgcn_mfma_f32_16x16x32_bf16(a1,b1,acc,0,0,0);
      #pragma unroll
      for(int r=0;r<4;r++)
        rws[(quad*4+r)*LSTR + col] = f2bf(acc[r]);
    }
  }
  __syncthreads();
  // ---- phase 2: TP per (edge,f); wave's two halves take edges 8 apart ----
  #pragma unroll
  for(int sub=0;sub<2;sub++){
    int le = le_base + sub*4;
    int el=el0+le;
    if(el>=ecnt) continue;
    int j=eb+el;
    int s = (sub==0)? s0 : s1;
    float hs[16];
    {
      const unsigned short* hp = hlin+(size_t)s*512+f*16;
      if (L0){
        hs[0]=bf2f(hp[0]);
        #pragma unroll
        for(int c=1;c<16;c++) hs[c]=0.f;
      } else {
        bf16x8 h0=*(const bf16x8*)hp;
        bf16x8 h1=*(const bf16x8*)(hp+8);
        #pragma unroll
        for(int c=0;c<8;c++){ hs[c]=bf2f((unsigned short)h0[c]); hs[8+c]=bf2f((unsigned short)h1[c]); }
      }
    }
    float yv[16];
    {
      const float4* yp=(const float4*)(Y+(size_t)j*16);
      float4 a=yp[0],b=yp[1],cc=yp[2],d=yp[3];
      yv[0]=a.x; yv[1]=a.y; yv[2]=a.z; yv[3]=a.w;
      yv[4]=b.x; yv[5]=b.y; yv[6]=b.z; yv[7]=b.w;
      yv[8]=cc.x; yv[9]=cc.y; yv[10]=cc.z; yv[11]=cc.w;
      yv[12]=d.x; yv[13]=d.y; yv[14]=d.z; yv[15]=d.w;
    }
    const unsigned short* rp = rws + le*LSTR + f;
    float acc[16];
    #pragma unroll
    for(int c=0;c<16;c++) acc[c]=0.f;
    tp_paths<L0,0>(hs,yv,rp,acc);
    bf16x8 m0, m1;
    #pragma unroll
    for(int c=0;c<8;c++){
      m0[c]=(short)f2bf(acc[c]*0.0625f);
      m1[c]=(short)f2bf(acc[8+c]*0.0625f);
    }
    bf16x8* mp=(bf16x8*)(msgs+(size_t)el*512+f*16);
    mp[0]=m0; mp[1]=m1;
  }
}

// ---------------- CSR segment-sum of bf16 messages (no atomics) ----------------
__global__ __launch_bounds__(256) void k_seg_sum(
    const unsigned short* __restrict__ msgs, const int* __restrict__ row,
    float* __restrict__ agg, int eb, int ecnt, int N)
{
  int t=blockIdx.x*256+threadIdx.x;
  int n=t>>6, q=t&63;            // q indexes 8 consecutive floats; wave = 1 node
  if(n>=N) return;
  int lo=row[n], hi=row[n+1];
  int a0 = lo>eb ? lo : eb;
  int a1e = eb+ecnt;
  int a1 = hi<a1e ? hi : a1e;
  if(a0>=a1) return;
  float s[8];
  #pragma unroll
  for(int i=0;i<8;i++) s[i]=0.f;
  for(int j=a0;j<a1;j++){
    bf16x8 v=*(const bf16x8*)(msgs+(size_t)(j-eb)*512+q*8);
    #pragma unroll
    for(int i=0;i<8;i++) s[i]+=bf2f((unsigned short)v[i]);
  }
  float* ap=agg+(size_t)n*512+q*8;
  float4* a0p=(float4*)ap;
  float4 o0=a0p[0], o1=a0p[1];
  o0.x+=s[0]; o0.y+=s[1]; o0.z+=s[2]; o0.w+=s[3];
  o1.x+=s[4]; o1.y+=s[5]; o1.z+=s[6]; o1.w+=s[7];
  a0p[0]=o0; a0p[1]=o1;
}

// ---------------- node-wise symmetric tensor product (product basis, full) ----------------
__global__ __launch_bounds__(256) void k_tp_node(
    const float* __restrict__ in, float* __restrict__ out,
    const float* __restrict__ pb, const int* __restrict__ z, int N)
{
  int t=blockIdx.x*256+threadIdx.x;
  int n=t>>5, f=t&31;
  if(n>=N) return;
  float A[16];
  {
    const float4* p=(const float4*)(in+(size_t)n*512+f*16);
    float4 a=p[0],b=p[1],c=p[2],d=p[3];
    A[0]=a.x; A[1]=a.y; A[2]=a.z; A[3]=a.w;
    A[4]=b.x; A[5]=b.y; A[6]=b.z; A[7]=b.w;
    A[8]=c.x; A[9]=c.y; A[10]=c.z; A[11]=c.w;
    A[12]=d.x; A[13]=d.y; A[14]=d.z; A[15]=d.w;
  }
  float B2[16]; float B3[16];
  #pragma unroll
  for(int c=0;c<16;c++){ B2[c]=0.f; B3[c]=0.f; }
  tpn_paths<0>(A,A,B2);
  tpn_paths<0>(B2,A,B3);
  int zz=z[n];
  float wa=pb[zz*96+f], wb=pb[zz*96+32+f], wc=pb[zz*96+64+f];
  float o[16];
  #pragma unroll
  for(int c=0;c<16;c++) o[c]=wa*A[c]+wb*B2[c]+wc*B3[c];
  float4* op=(float4*)(out+(size_t)n*512+f*16);
  op[0]=make_float4(o[0],o[1],o[2],o[3]);
  op[1]=make_float4(o[4],o[5],o[6],o[7]);
  op[2]=make_float4(o[8],o[9],o[10],o[11]);
  op[3]=make_float4(o[12],o[13],o[14],o[15]);
}

// ---------------- node TP, scalar-output only (layer 1: only 0e reaches readout) ----------------
__global__ __launch_bounds__(256) void k_tp_node_sc(
    const float* __restrict__ in, float* __restrict__ out,
    const float* __restrict__ pb, const int* __restrict__ z, int N)
{
  int t=blockIdx.x*256+threadIdx.x;
  int n=t>>5, f=t&31;
  if(n>=N) return;
  float A[16];
  {
    const float4* p=(const float4*)(in+(size_t)n*512+f*16);
    float4 a=p[0],b=p[1],c=p[2],d=p[3];
    A[0]=a.x; A[1]=a.y; A[2]=a.z; A[3]=a.w;
    A[4]=b.x; A[5]=b.y; A[6]=b.z; A[7]=b.w;
    A[8]=c.x; A[9]=c.y; A[10]=c.z; A[11]=c.w;
    A[12]=d.x; A[13]=d.y; A[14]=d.z; A[15]=d.w;
  }
  float B2[16];
  #pragma unroll
  for(int c=0;c<16;c++) B2[c]=0.f;
  tpn_paths<0>(A,A,B2);
  float B3_0 = tpn_scalar(B2,A);
  int zz=z[n];
  float wa=pb[zz*96+f], wb=pb[zz*96+32+f], wc=pb[zz*96+64+f];
  out[(size_t)n*32+f] = wa*A[0]+wb*B2[0]+wc*B3_0;
}

// ---------------- merged readout: e0 dot + residual matmul ----------------
__global__ __launch_bounds__(256) void k_readout(
    const float* __restrict__ feats, const float* __restrict__ ro0,
    const float* __restrict__ res1, const int* __restrict__ z,
    float* __restrict__ e0, float* __restrict__ resid, int N)
{
  int t=blockIdx.x*256+threadIdx.x;
  int n=t>>5, g=t&31;
  if(n>=N) return;
  const float* wp=res1+(size_t)z[n]*1024;
  float a=0.f;
  #pragma unroll 8
  for(int f=0;f<32;f++) a=fmaf(feats[(size_t)n*512+f*16], wp[(f<<5)+g], a);
  resid[(size_t)n*32+g]=a;
  if(g==0){
    float b=0.f;
    #pragma unroll 8
    for(int f=0;f<32;f++) b=fmaf(feats[(size_t)n*512+f*16], ro0[f], b);
    e0[n]=b;
  }
}

__global__ __launch_bounds__(256) void k_final(
    const float* __restrict__ hsc, const float* __restrict__ resid,
    const float* __restrict__ e0a, const float* __restrict__ ro1a,
    const float* __restrict__ ro1b, float* __restrict__ out, int N)
{
  int t=blockIdx.x*256+threadIdx.x;
  float val=0.f;
  if (t<N){
    float sc[32];
    #pragma unroll 8
    for(int f=0;f<32;f++) sc[f]=hsc[(size_t)t*32+f]+resid[(size_t)t*32+f];
    float e1=0.f;
    #pragma unroll
    for(int j=0;j<16;j++){
      float a=0.f;
      #pragma unroll
      for(int f=0;f<32;f++) a=fmaf(sc[f],ro1a[f*16+j],a);
      float s=a/(1.f+__expf(-a));
      e1=fmaf(s,ro1b[j],e1);
    }
    val = -1.5f + 2.0f*(e0a[t]+e1) - 10.0f;
  }
  __shared__ float red[256];
  red[threadIdx.x]=val;
  __syncthreads();
  for(int s=128;s>0;s>>=1){
    if(threadIdx.x<s) red[threadIdx.x]+=red[threadIdx.x+s];
    __syncthreads();
  }
  if(threadIdx.x==0) atomicAdd(out, red[0]);
}

// ---------------- host orchestration ----------------
extern "C" void kernel_launch(void* const* d_in, const int* in_sizes, int n_in,
                              void* d_out, int out_size, void* d_ws, size_t ws_size,
                              hipStream_t stream)
{
  const float* vec   =(const float*)d_in[0];
  const int*   zarr  =(const int*)  d_in[1];
  const int*   snd   =(const int*)  d_in[2];
  const int*   rcv   =(const int*)  d_in[3];
  const float* embed =(const float*)d_in[4];
  const float* r0w0  =(const float*)d_in[5];
  const float* r0w1  =(const float*)d_in[6];
  const float* r0w2  =(const float*)d_in[7];
  const float* up0   =(const float*)d_in[8];
  const float* post0 =(const float*)d_in[9];
  const float* pb0   =(const float*)d_in[10];
  const float* pblin0=(const float*)d_in[11];
  const float* r1w0  =(const float*)d_in[12];
  const float* r1w1  =(const float*)d_in[13];
  const float* r1w2  =(const float*)d_in[14];
  const float* up1   =(const float*)d_in[15];
  const float* post1 =(const float*)d_in[16];
  const float* pb1   =(const float*)d_in[17];
  const float* pblin1=(const float*)d_in[18];
  const float* sel0  =(const float*)d_in[19];
  const float* ro0   =(const float*)d_in[20];
  const float* res1  =(const float*)d_in[21];
  const float* ro1a  =(const float*)d_in[22];
  const float* ro1b  =(const float*)d_in[23];

  const int E = in_sizes[0]/3;
  const int N = in_sizes[1];
  const int Epad = (E+63)&~63;

  char* ws=(char*)d_ws;
  size_t o=0;
  auto alloc=[&](size_t bytes)->char*{
    char* p=ws+o;
    o=(o+bytes+255)&~(size_t)255;
    return p;
  };
  int*   deg  =(int*)  alloc((size_t)N*4);
  int*   rowp =(int*)  alloc((size_t)(N+1)*4);
  int*   cur  =(int*)  alloc((size_t)N*4);
  int*   eid  =(int*)  alloc((size_t)E*4);
  int*   snd_s=(int*)  alloc((size_t)E*4);
  float* Yb   =(float*)alloc((size_t)E*16*4);
  float* radb =(float*)alloc((size_t)E*8*4);
  unsigned short* hidb=(unsigned short*)alloc((size_t)(Epad+16)*64*2);
  unsigned short* w2t0=(unsigned short*)alloc((size_t)1088*64*2);
  unsigned short* w2t1=(unsigned short*)alloc((size_t)1088*64*2);
  unsigned short* hl16=(unsigned short*)alloc((size_t)N*512*2);
  float* combw=(float*)alloc((size_t)10*4096*4);
  float* feats=(float*)alloc((size_t)N*512*4);
  float* bufA =(float*)alloc((size_t)N*512*4);
  float* bufB =(float*)alloc((size_t)N*512*4);
  float* bufC =(float*)alloc((size_t)N*512*4);
  float* e0b  =(float*)alloc((size_t)N*4);
  float* residb=(float*)alloc((size_t)N*32*4);
  float* scA  =(float*)alloc((size_t)N*32*4);
  float* scB  =(float*)alloc((size_t)N*32*4);
  char*  dyn  = ws+o;
  size_t remain = ws_size>o ? ws_size-o : 0;

  dim3 tb(256);
  dim3 nblk((unsigned)((N*32+255)/256));
  dim3 eblk((unsigned)((E+255)/256));
  dim3 qblk((unsigned)((N*64+255)/256));

  // CSR build (receiver-sorted edge order)
  hipMemsetAsync(deg,0,(size_t)N*4,stream);
  k_count<<<eblk,tb,0,stream>>>(rcv,deg,E);
  k_scan<<<dim3(1),dim3(1024),0,stream>>>(deg,rowp,cur,N);
  k_fill<<<eblk,tb,0,stream>>>(rcv,cur,eid,E);

  k_edge_setup<<<eblk,tb,0,stream>>>(vec,snd,eid,Yb,radb,snd_s,E);
  k_node_init<<<nblk,tb,0,stream>>>(embed,zarr,feats,N);

  // weight preprocessing (per launch)
  k_cast2<<<dim3((2*1088*64+255)/256),tb,0,stream>>>(r0w2,r1w2,w2t0,w2t1);
  k_wcomb<<<dim3((10*4096+255)/256),tb,0,stream>>>(post0,sel0,combw);

  auto run_edges=[&](bool l0, const unsigned short* hlin, const unsigned short* w2t, float* agg){
    long rows = (long)(remain/1024);
    rows -= rows%64;
    if (rows>(long)Epad) rows=Epad;
    if (rows<64) rows=64;
    unsigned short* msgsb = (unsigned short*)dyn;
    for(long eb=0;eb<E;eb+=rows){
      long cnt = E-eb; if(cnt>rows) cnt=rows;
      dim3 g2((unsigned)((cnt+15)/16));
      if(l0) k_tp_fused<true ><<<g2,tb,0,stream>>>(hlin,Yb,hidb+(size_t)eb*64,w2t,snd_s,msgsb,(int)eb,(int)cnt);
      else   k_tp_fused<false><<<g2,tb,0,stream>>>(hlin,Yb,hidb+(size_t)eb*64,w2t,snd_s,msgsb,(int)eb,(int)cnt);
      k_seg_sum<<<qblk,tb,0,stream>>>(msgsb,rowp,agg,(int)eb,(int)cnt,N);
    }
  };

  // ---- layer 0 ----
  k_lin16<<<nblk,tb,0,stream>>>(feats,hl16,up0,N);
  k_radial<<<eblk,tb,0,stream>>>(radb,r0w0,r0w1,hidb,E);
  hipMemsetAsync(bufB,0,(size_t)N*512*4,stream);
  run_edges(true,hl16,w2t0,bufB);
  k_lin<<<nblk,tb,0,stream>>>(bufB,bufA,combw,zarr,4096,N);   // post0+sel0 combined
  k_tp_node<<<nblk,tb,0,stream>>>(bufA,bufB,pb0,zarr,N);
  k_lin<<<nblk,tb,0,stream>>>(bufB,feats,pblin0,(const int*)nullptr,0,N);
  k_readout<<<nblk,tb,0,stream>>>(feats,ro0,res1,zarr,e0b,residb,N);

  // ---- layer 1 ----
  k_lin16<<<nblk,tb,0,stream>>>(feats,hl16,up1,N);
  k_radial<<<eblk,tb,0,stream>>>(radb,r1w0,r1w1,hidb,E);
  hipMemsetAsync(bufC,0,(size_t)N*512*4,stream);
  run_edges(false,hl16,w2t1,bufC);
  k_lin<<<nblk,tb,0,stream>>>(bufC,bufB,post1,(const int*)nullptr,0,N);
  k_tp_node_sc<<<nblk,tb,0,stream>>>(bufB,scA,pb1,zarr,N);
  k_lin_sc<<<nblk,tb,0,stream>>>(scA,scB,pblin1,N);
  hipMemsetAsync(d_out,0,4,stream);
  k_final<<<dim3((N+255)/256),tb,0,stream>>>(scB,residb,e0b,ro1a,ro1b,(float*)d_out,N);
}

// Round 14
// 764.290 us; speedup vs baseline: 3.0740x; 1.1690x over previous
//
#include <hip/hip_runtime.h>
#include <math.h>

// ---------------- static config ----------------
#define NF 32
#define NPATHS 34

typedef __attribute__((ext_vector_type(8))) short bf16x8;
typedef __attribute__((ext_vector_type(4))) float f32x4;

__device__ __forceinline__ unsigned short f2bf(float v){
  unsigned u = __float_as_uint(v);
  u += 0x7fffu + ((u>>16)&1u);
  return (unsigned short)(u>>16);
}
__device__ __forceinline__ float bf2f(unsigned short h){
  return __uint_as_float(((unsigned)h)<<16);
}

struct PathTab { int l1[NPATHS]; int l2[NPATHS]; int l3[NPATHS]; };
constexpr PathTab mkpaths(){
  PathTab t{}; int n=0;
  for(int a=0;a<=3;a++)for(int b=0;b<=3;b++)for(int c=0;c<=3;c++){
    int lo = a>b ? a-b : b-a;
    if(c>=lo && c<=a+b){ t.l1[n]=a; t.l2[n]=b; t.l3[n]=c; n++; }
  }
  return t;
}
constexpr PathTab PT = mkpaths();

// ---------------- compile-time Wigner-3j (exact replica of reference math) ----------------
struct FactT { double v[22]; };
constexpr FactT mkfactT(){ FactT f{}; f.v[0]=1.0; for(int i=1;i<22;i++) f.v[i]=f.v[i-1]*(double)i; return f; }
constexpr FactT FT = mkfactT();
constexpr double cfact(int n){ return FT.v[n]; }

constexpr double csqrt(double x){
  if(x<=0.0) return 0.0;
  double g = x<1.0 ? 1.0 : x;
  for(int i=0;i<40;i++) g=0.5*(g+x/g);
  return g;
}

constexpr double su2cg(int j1,int j2,int j3,int m1,int m2){
  int m3=m1+m2;
  if(m3<-j3||m3>j3) return 0.0;
  double pref = (double)(2*j3+1)*cfact(j3+j1-j2)*cfact(j3-j1+j2)*cfact(j1+j2-j3)/cfact(j1+j2+j3+1);
  pref *= cfact(j3+m3)*cfact(j3-m3)*cfact(j1-m1)*cfact(j1+m1)*cfact(j2-m2)*cfact(j2+m2);
  pref = csqrt(pref);
  int k0=0; if(j2-j3-m1>k0)k0=j2-j3-m1; if(j1-j3+m2>k0)k0=j1-j3+m2;
  int k1=j1+j2-j3; if(j1-m1<k1)k1=j1-m1; if(j2+m2<k1)k1=j2+m2;
  double s=0.0;
  for(int k=k0;k<=k1;k++){
    double d = cfact(k)*cfact(j1+j2-j3-k)*cfact(j1-m1-k)*cfact(j2+m2-k)*cfact(j3-j2+m1+k)*cfact(j3-j1-m2+k);
    s += (k&1)? -1.0/d : 1.0/d;
  }
  return pref*s;
}

struct ccd { double x, y; };
constexpr ccd cqval(int l,int r,int col){
  const double is2 = 0.70710678118654752440;
  double re=0.0, im=0.0;
  if (r<l){ if (col==2*l-r) re=is2; else if (col==r) im=-is2; }
  else if (r==l){ if (col==l) re=1.0; }
  else { double s = ((r-l)&1)? -1.0:1.0;
         if (col==r) re=s*is2; else if (col==2*l-r) im=s*is2; }
  ccd v{re,im};
  switch(l&3){           // multiply by (-i)^l
    case 1: return ccd{ v.y, -v.x };
    case 2: return ccd{-v.x, -v.y };
    case 3: return ccd{-v.y,  v.x };
    default: return v;
  }
}

constexpr double w3entry(int l1,int l2,int l3,int i,int j,int k){
  double re=0.0;
  for(int a=0;a<2*l1+1;a++){
    ccd qa=cqval(l1,a,i); if(qa.x==0.0&&qa.y==0.0) continue;
    for(int b=0;b<2*l2+1;b++){
      ccd qb=cqval(l2,b,j); if(qb.x==0.0&&qb.y==0.0) continue;
      int m1=a-l1, m2=b-l2, m3=m1+m2;
      if(m3<-l3||m3>l3) continue;
      int c=m3+l3;
      double cg=su2cg(l1,l2,l3,m1,m2); if(cg==0.0) continue;
      ccd qc=cqval(l3,c,k); qc.y=-qc.y;   // conj
      if(qc.x==0.0&&qc.y==0.0) continue;
      ccd ab{qa.x*qb.x-qa.y*qb.y, qa.x*qb.y+qa.y*qb.x};
      re += cg*(ab.x*qc.x - ab.y*qc.y);
    }
  }
  return re;
}

template<int L1,int L2,int L3> struct W3Arr { float v[(2*L1+1)*(2*L2+1)*(2*L3+1)]; };
template<int L1,int L2,int L3> constexpr W3Arr<L1,L2,L3> mkW3(double scale){
  W3Arr<L1,L2,L3> r{};
  for(int i=0;i<2*L1+1;i++)
    for(int j=0;j<2*L2+1;j++)
      for(int k=0;k<2*L3+1;k++)
        r.v[(i*(2*L2+1)+j)*(2*L3+1)+k] = (float)(w3entry(L1,L2,L3,i,j,k)*scale);
  return r;
}
template<int L1,int L2,int L3> constexpr W3Arr<L1,L2,L3> W3V = mkW3<L1,L2,L3>(1.0);
template<int L1,int L2,int L3> constexpr W3Arr<L1,L2,L3> W3N = mkW3<L1,L2,L3>(1.0/csqrt(2.0*L3+1.0));

// SH recursion scales (replica of reference _sh_scales, float64 like numpy)
struct SCt { double sc2, sc3; };
constexpr SCt mksc(){
  double v0=0.2,v1=-0.6,v2=0.7;
  double nv=csqrt(v0*v0+v1*v1+v2*v2);
  double s3=csqrt(3.0);
  double y1[3]={s3*v0/nv, s3*v1/nv, s3*v2/nv};
  double t2[5]={0,0,0,0,0}; double n2=0.0;
  for(int c=0;c<5;c++){
    double s=0.0;
    for(int a=0;a<3;a++)for(int b=0;b<3;b++) s += w3entry(1,1,2,a,b,c)*y1[a]*y1[b];
    t2[c]=s; n2+=s*s;
  }
  double sc2=csqrt(5.0)/csqrt(n2);
  double y2[5]={sc2*t2[0],sc2*t2[1],sc2*t2[2],sc2*t2[3],sc2*t2[4]};
  double n3=0.0;
  for(int c=0;c<7;c++){
    double s=0.0;
    for(int a=0;a<5;a++)for(int b=0;b<3;b++) s += w3entry(2,1,3,a,b,c)*y2[a]*y1[b];
    n3+=s*s;
  }
  double sc3=csqrt(7.0)/csqrt(n3);
  return SCt{sc2,sc3};
}
constexpr SCt SCV = mksc();

// ---------------- template-unrolled TP with literal W3J, true-zero elision ----------------
template<bool NORM,int l1,int l2,int l3,int A,int B,int C>
__device__ __forceinline__ void w3term(const float* __restrict__ x, const float* __restrict__ y,
                                       float rv, float* __restrict__ acc){
  constexpr float w = NORM ? W3N<l1,l2,l3>.v[(A*(2*l2+1)+B)*(2*l3+1)+C]
                           : W3V<l1,l2,l3>.v[(A*(2*l2+1)+B)*(2*l3+1)+C];
  if constexpr (w!=0.0f)
    acc[l3*l3+C] = fmaf(w, x[l1*l1+A]*y[l2*l2+B]*rv, acc[l3*l3+C]);
}
template<bool NORM,int l1,int l2,int l3,int A,int B,int C>
__device__ __forceinline__ void w3loopC(const float* x,const float* y,float rv,float* acc){
  if constexpr (C<2*l3+1){
    w3term<NORM,l1,l2,l3,A,B,C>(x,y,rv,acc);
    w3loopC<NORM,l1,l2,l3,A,B,C+1>(x,y,rv,acc);
  }
}
template<bool NORM,int l1,int l2,int l3,int A,int B>
__device__ __forceinline__ void w3loopB(const float* x,const float* y,float rv,float* acc){
  if constexpr (B<2*l2+1){
    w3loopC<NORM,l1,l2,l3,A,B,0>(x,y,rv,acc);
    w3loopB<NORM,l1,l2,l3,A,B+1>(x,y,rv,acc);
  }
}
template<bool NORM,int l1,int l2,int l3,int A>
__device__ __forceinline__ void w3loopA(const float* x,const float* y,float rv,float* acc){
  if constexpr (A<2*l1+1){
    w3loopB<NORM,l1,l2,l3,A,0>(x,y,rv,acc);
    w3loopA<NORM,l1,l2,l3,A+1>(x,y,rv,acc);
  }
}

// factored form: S[C] += w * (x*y); rv applied once per output (edge TP hot loop)
template<int l1,int l2,int l3,int A,int B,int C>
__device__ __forceinline__ void w3termS(const float* __restrict__ x, const float* __restrict__ y,
                                        float* __restrict__ S){
  constexpr float w = W3V<l1,l2,l3>.v[(A*(2*l2+1)+B)*(2*l3+1)+C];
  if constexpr (w!=0.0f)
    S[C] = fmaf(w, x[l1*l1+A]*y[l2*l2+B], S[C]);
}
template<int l1,int l2,int l3,int A,int B,int C>
__device__ __forceinline__ void w3loopSC(const float* x,const float* y,float* S){
  if constexpr (C<2*l3+1){
    w3termS<l1,l2,l3,A,B,C>(x,y,S);
    w3loopSC<l1,l2,l3,A,B,C+1>(x,y,S);
  }
}
template<int l1,int l2,int l3,int A,int B>
__device__ __forceinline__ void w3loopSB(const float* x,const float* y,float* S){
  if constexpr (B<2*l2+1){
    w3loopSC<l1,l2,l3,A,B,0>(x,y,S);
    w3loopSB<l1,l2,l3,A,B+1>(x,y,S);
  }
}
template<int l1,int l2,int l3,int A>
__device__ __forceinline__ void w3loopSA(const float* x,const float* y,float* S){
  if constexpr (A<2*l1+1){
    w3loopSB<l1,l2,l3,A,0>(x,y,S);
    w3loopSA<l1,l2,l3,A+1>(x,y,S);
  }
}

template<bool L0,int P>
__device__ __forceinline__ void tp_paths(const float* hs,const float* yv,
                                         const unsigned short* rp, float* acc){
  if constexpr (P<NPATHS){
    constexpr int l1=PT.l1[P], l2=PT.l2[P], l3=PT.l3[P];
    if constexpr (!(L0 && l1!=0)){
      float S[2*l3+1];
      #pragma unroll
      for(int c=0;c<2*l3+1;c++) S[c]=0.f;
      w3loopSA<l1,l2,l3,0>(hs,yv,S);
      float rv = bf2f(rp[P*32]);
      #pragma unroll
      for(int c=0;c<2*l3+1;c++) acc[l3*l3+c]=fmaf(rv,S[c],acc[l3*l3+c]);
    }
    tp_paths<L0,P+1>(hs,yv,rp,acc);
  }
}

template<int P>
__device__ __forceinline__ void tpn_paths(const float* x,const float* y,float* o){
  if constexpr (P<NPATHS){
    constexpr int l1=PT.l1[P], l2=PT.l2[P], l3=PT.l3[P];
    w3loopA<true,l1,l2,l3,0>(x,y,1.0f,o);
    tpn_paths<P+1>(x,y,o);
  }
}

// scalar-only node TP: l3=0 paths (l,l,0) only
__device__ __forceinline__ float tpn_scalar(const float* x,const float* y){
  float o[1]={0.f};
  w3loopA<true,0,0,0,0>(x,y,1.0f,o);
  w3loopA<true,1,1,0,0>(x,y,1.0f,o);
  w3loopA<true,2,2,0,0>(x,y,1.0f,o);
  w3loopA<true,3,3,0,0>(x,y,1.0f,o);
  return o[0];
}

// ---------------- CSR build: degree count, scan, fill ----------------
__global__ __launch_bounds__(256) void k_count(
    const int* __restrict__ rcv, int* __restrict__ deg, int E)
{
  int e=blockIdx.x*256+threadIdx.x;
  if(e>=E) return;
  atomicAdd(&deg[rcv[e]],1);
}

#define SCAN_PER 32
__global__ __launch_bounds__(1024) void k_scan(
    const int* __restrict__ deg, int* __restrict__ row,
    int* __restrict__ cur, int N)
{
  __shared__ int part[1024];
  int t=threadIdx.x;
  int per=(N+1023)/1024; if(per>SCAN_PER) per=SCAN_PER;
  int base=t*per;
  int loc[SCAN_PER];
  int s=0;
  for(int i=0;i<per;i++){ int idx=base+i; int v=(idx<N)? deg[idx]:0; loc[i]=s; s+=v; }
  part[t]=s;
  __syncthreads();
  for(int off=1;off<1024;off<<=1){
    int v=(t>=off)? part[t-off]:0;
    __syncthreads();
    part[t]+=v;
    __syncthreads();
  }
  int ex=(t==0)?0:part[t-1];
  for(int i=0;i<per;i++){
    int idx=base+i;
    if(idx<N){ int r=ex+loc[i]; row[idx]=r; cur[idx]=r; }
  }
  if(t==1023) row[N]=part[1023];
}

__global__ __launch_bounds__(256) void k_fill(
    const int* __restrict__ rcv, int* __restrict__ cur,
    int* __restrict__ eid, int E)
{
  int e=blockIdx.x*256+threadIdx.x;
  if(e>=E) return;
  int pos=atomicAdd(&cur[rcv[e]],1);
  eid[pos]=e;
}

// ---------------- per-edge geometry (receiver-sorted order): SH + radial basis ----------------
__global__ __launch_bounds__(256) void k_edge_setup(
    const float* __restrict__ vec, const int* __restrict__ snd,
    const int* __restrict__ eid, float* __restrict__ Y,
    float* __restrict__ rad, int* __restrict__ snd_s, int E)
{
  int j = blockIdx.x*256+threadIdx.x;
  if (j>=E) return;
  int e = eid[j];
  snd_s[j]=snd[e];
  float vx=vec[3*e], vy=vec[3*e+1], vz=vec[3*e+2];
  float r=sqrtf(vx*vx+vy*vy+vz*vz);
  float inv=1.0f/fmaxf(r,1e-9f);
  float y[16];
  y[0]=1.0f;
  const float s3=1.7320508075688772f;
  y[1]=s3*vx*inv; y[2]=s3*vy*inv; y[3]=s3*vz*inv;
  constexpr float sc2=(float)SCV.sc2, sc3=(float)SCV.sc3;
  {
    float t[16];
    #pragma unroll
    for(int c=0;c<16;c++) t[c]=0.f;
    w3loopA<false,1,1,2,0>(y,y,1.0f,t);
    #pragma unroll
    for(int c=0;c<5;c++) y[4+c]=sc2*t[4+c];
    w3loopA<false,2,1,3,0>(y,y,1.0f,t);
    #pragma unroll
    for(int c=0;c<7;c++) y[9+c]=sc3*t[9+c];
  }
  float4* Yp=(float4*)(Y+(size_t)j*16);
  Yp[0]=make_float4(y[0],y[1],y[2],y[3]);
  Yp[1]=make_float4(y[4],y[5],y[6],y[7]);
  Yp[2]=make_float4(y[8],y[9],y[10],y[11]);
  Yp[3]=make_float4(y[12],y[13],y[14],y[15]);
  float x = r*0.2f;
  float env=0.f;
  if (x<1.0f){
    float x2=x*x; float x4=x2*x2; float x5=x4*x;
    env = 1.0f - 21.0f*x5 + 35.0f*x5*x - 15.0f*x5*x2;
  }
  const float cb = 0.632455532033675866f; // sqrt(2/5)
  float base = inv*env*cb;
  #pragma unroll
  for(int n=1;n<=8;n++)
    rad[(size_t)j*8 + n-1] = base*sinf(3.14159265358979323846f * x * (float)n);
}

// ---------------- layer-0 hlin directly from scalar embedding (bf16) ----------------
__global__ __launch_bounds__(256) void k_embed16(
    const float* __restrict__ embed, const float* __restrict__ up0,
    const int* __restrict__ z, unsigned short* __restrict__ hl16, int N)
{
  int t=blockIdx.x*256+threadIdx.x;
  int n=t>>5, g=t&31;
  if(n>=N) return;
  const float* ep=embed+z[n]*32;
  float a=0.f;
  #pragma unroll 8
  for(int f=0;f<32;f++) a=fmaf(ep[f],up0[(f<<5)+g],a);
  bf16x8 o0={(short)f2bf(a),0,0,0,0,0,0,0};
  bf16x8 o1={0,0,0,0,0,0,0,0};
  bf16x8* op=(bf16x8*)(hl16+(size_t)n*512+g*16);
  op[0]=o0; op[1]=o1;
}

// ---------------- radial MLP hidden layers (bf16 output) ----------------
__global__ __launch_bounds__(256) void k_radial(
    const float* __restrict__ rad, const float* __restrict__ w0,
    const float* __restrict__ w1, unsigned short* __restrict__ hid, int E)
{
  __shared__ float w0s[8*64];
  __shared__ float w1s[64*64];
  int tid=threadIdx.x;
  for(int i=tid;i<512;i+=256) w0s[i]=w0[i];
  for(int i=tid;i<4096;i+=256) w1s[i]=w1[i];
  __syncthreads();
  int e=blockIdx.x*256+tid;
  if(e>=E) return;
  const float4* rp=(const float4*)(rad+(size_t)e*8);
  float4 ra=rp[0], rb=rp[1];
  float rv[8]={ra.x,ra.y,ra.z,ra.w,rb.x,rb.y,rb.z,rb.w};
  float h1[64];
  #pragma unroll 8
  for(int j=0;j<64;j++){
    float a=0.f;
    #pragma unroll
    for(int i=0;i<8;i++) a=fmaf(rv[i],w0s[i*64+j],a);
    h1[j]=a/(1.f+__expf(-a));
  }
  unsigned short* hp = hid+(size_t)e*64;
  #pragma unroll 4
  for(int j=0;j<64;j++){
    float a=0.f;
    #pragma unroll
    for(int i=0;i<64;i++) a=fmaf(h1[i],w1s[i*64+j],a);
    hp[j]=f2bf(a/(1.f+__expf(-a)));
  }
}

// ---------------- weight prep: cast+transpose both w2, and comb = post0@sel0 ----------------
__global__ __launch_bounds__(256) void k_prep(
    const float* __restrict__ w2a, const float* __restrict__ w2b,
    unsigned short* __restrict__ ta, unsigned short* __restrict__ tb,
    const float* __restrict__ post0, const float* __restrict__ sel0,
    float* __restrict__ comb)
{
  int t=blockIdx.x*256+threadIdx.x;
  const int C2=2*1088*64;
  if(t<C2){
    const float* src = (t<1088*64)? w2a : w2b;
    unsigned short* dst = (t<1088*64)? ta : tb;
    int u = (t<1088*64)? t : t-1088*64;
    int c=u>>6, k=u&63;
    dst[(size_t)c*64+k]=f2bf(src[(size_t)k*1088+c]);
  } else {
    int u=t-C2;
    if(u<10*4096){
      int z=u>>12, r=u&4095;
      int l=r>>10, e=(r>>5)&31, g=r&31;
      const float* pp=post0+l*1024+e*32;
      const float* sp=sel0+(size_t)z*4096+l*1024;
      float a=0.f;
      #pragma unroll 8
      for(int f=0;f<32;f++) a=fmaf(pp[f], sp[f*32+g], a);
      comb[(size_t)z*4096 + l*1024 + e*32 + g]=a;
    }
  }
}

// ---------------- FUSED: MFMA rw-GEMM (to LDS) + edge tensor product -> messages ----------------
// Known-good config (R12/R13): LSTR ≡ 4 mod 16 -> 0 bank conflicts; snd hoisted;
// NO launch_bounds min-waves (R11: forced VGPR=64 spilled 6.8GB).
template<bool L0>
__global__ __launch_bounds__(256) void k_tp_fused(
    const unsigned short* __restrict__ hlin, const float* __restrict__ Y,
    const unsigned short* __restrict__ hid, const unsigned short* __restrict__ w2t,
    const int* __restrict__ snd_s, unsigned short* __restrict__ msgs,
    int eb, int ecnt)
{
  constexpr int RWLD = L0 ? 128 : 1088;
  constexpr int LSTR = L0 ? 132 : 1092;
  __shared__ unsigned short rws[16*LSTR];
  int tid=threadIdx.x;
  int lane=tid&63, wave=tid>>6;
  int m16=lane&15, quad=lane>>4;
  int el0=blockIdx.x*16;
  int f=tid&31;
  int w=tid>>6, hb=(tid>>5)&1;
  int le_base = w + hb*8;
  int el_s0 = el0 + le_base;
  int el_s1 = el0 + le_base + 4;
  int s0 = (el_s0<ecnt)? snd_s[eb+el_s0] : 0;
  int s1 = (el_s1<ecnt)? snd_s[eb+el_s1] : 0;
  {
    const unsigned short* Ab = hid + (size_t)el0*64;
    bf16x8 a0 = *(const bf16x8*)(Ab + m16*64 + quad*8);
    bf16x8 a1 = *(const bf16x8*)(Ab + m16*64 + 32 + quad*8);
    #pragma unroll 2
    for(int nt=wave; nt<RWLD/16; nt+=4){
      int col = nt*16 + m16;
      bf16x8 b0 = *(const bf16x8*)(w2t + (size_t)col*64 + quad*8);
      bf16x8 b1 = *(const bf16x8*)(w2t + (size_t)col*64 + 32 + quad*8);
      f32x4 acc = (f32x4){0.f,0.f,0.f,0.f};
      acc = __builtin_amdgcn_mfma_f32_16x16x32_bf16(a0,b0,acc,0,0,0);
      acc = __builtin_amdgcn_mfma_f32_16x16x32_bf16(a1,b1,acc,0,0,0);
      #pragma unroll
      for(int r=0;r<4;r++)
        rws[(quad*4+r)*LSTR + col] = f2bf(acc[r]);
    }
  }
  __syncthreads();
  #pragma unroll
  for(int sub=0;sub<2;sub++){
    int le = le_base + sub*4;
    int el=el0+le;
    if(el>=ecnt) continue;
    int j=eb+el;
    int s = (sub==0)? s0 : s1;
    float hs[16];
    {
      const unsigned short* hp = hlin+(size_t)s*512+f*16;
      if (L0){
        hs[0]=bf2f(hp[0]);
        #pragma unroll
        for(int c=1;c<16;c++) hs[c]=0.f;
      } else {
        bf16x8 h0=*(const bf16x8*)hp;
        bf16x8 h1=*(const bf16x8*)(hp+8);
        #pragma unroll
        for(int c=0;c<8;c++){ hs[c]=bf2f((unsigned short)h0[c]); hs[8+c]=bf2f((unsigned short)h1[c]); }
      }
    }
    float yv[16];
    {
      const float4* yp=(const float4*)(Y+(size_t)j*16);
      float4 a=yp[0],b=yp[1],cc=yp[2],d=yp[3];
      yv[0]=a.x; yv[1]=a.y; yv[2]=a.z; yv[3]=a.w;
      yv[4]=b.x; yv[5]=b.y; yv[6]=b.z; yv[7]=b.w;
      yv[8]=cc.x; yv[9]=cc.y; yv[10]=cc.z; yv[11]=cc.w;
      yv[12]=d.x; yv[13]=d.y; yv[14]=d.z; yv[15]=d.w;
    }
    const unsigned short* rp = rws + le*LSTR + f;
    float acc[16];
    #pragma unroll
    for(int c=0;c<16;c++) acc[c]=0.f;
    tp_paths<L0,0>(hs,yv,rp,acc);
    bf16x8 m0, m1;
    #pragma unroll
    for(int c=0;c<8;c++){
      m0[c]=(short)f2bf(acc[c]*0.0625f);
      m1[c]=(short)f2bf(acc[8+c]*0.0625f);
    }
    bf16x8* mp=(bf16x8*)(msgs+(size_t)el*512+f*16);
    mp[0]=m0; mp[1]=m1;
  }
}

// ---------------- CSR segment-sum of bf16 messages (no atomics) ----------------
// INIT: first chunk writes agg directly (covers empty nodes too) — no memset needed.
template<bool INIT>
__global__ __launch_bounds__(256) void k_seg_sum(
    const unsigned short* __restrict__ msgs, const int* __restrict__ row,
    float* __restrict__ agg, int eb, int ecnt, int N)
{
  int t=blockIdx.x*256+threadIdx.x;
  int n=t>>6, q=t&63;
  if(n>=N) return;
  int lo=row[n], hi=row[n+1];
  int a0 = lo>eb ? lo : eb;
  int a1e = eb+ecnt;
  int a1 = hi<a1e ? hi : a1e;
  if(!INIT && a0>=a1) return;
  float s[8];
  #pragma unroll
  for(int i=0;i<8;i++) s[i]=0.f;
  for(int j=a0;j<a1;j++){
    bf16x8 v=*(const bf16x8*)(msgs+(size_t)(j-eb)*512+q*8);
    #pragma unroll
    for(int i=0;i<8;i++) s[i]+=bf2f((unsigned short)v[i]);
  }
  float4* a0p=(float4*)(agg+(size_t)n*512+q*8);
  if(INIT){
    a0p[0]=make_float4(s[0],s[1],s[2],s[3]);
    a0p[1]=make_float4(s[4],s[5],s[6],s[7]);
  } else {
    float4 o0=a0p[0], o1=a0p[1];
    o0.x+=s[0]; o0.y+=s[1]; o0.z+=s[2]; o0.w+=s[3];
    o1.x+=s[4]; o1.y+=s[5]; o1.z+=s[6]; o1.w+=s[7];
    a0p[0]=o0; a0p[1]=o1;
  }
}

// ---------------- fused layer-0 node chain: lin(comb)+tp_node(pb0)+pblin0+readout+up1->hl16 ----------------
__global__ __launch_bounds__(256) void k_node0(
    const float* __restrict__ agg, const float* __restrict__ combw,
    const float* __restrict__ pb0, const float* __restrict__ pblin0,
    const float* __restrict__ ro0, const float* __restrict__ res1,
    const float* __restrict__ up1, const int* __restrict__ z,
    float* __restrict__ e0, float* __restrict__ resid,
    unsigned short* __restrict__ hl16, int N)
{
  __shared__ float sh1[8*512] __attribute__((aligned(16)));
  __shared__ float sh2[8*512] __attribute__((aligned(16)));
  int tid=threadIdx.x;
  int n0=tid>>5, g=tid&31;
  int n=blockIdx.x*8+n0;
  bool act=(n<N);
  int zz = act? z[n] : 0;
  if(act){
    const float* wp = combw + (size_t)zz*4096;
    const float* ip = agg + (size_t)n*512;
    float A[16];
    #pragma unroll
    for(int c=0;c<16;c++) A[c]=0.f;
    #pragma unroll 8
    for(int f=0;f<NF;f++){
      const float4* xp=(const float4*)(ip+f*16);
      float4 x0=xp[0],x1=xp[1],x2=xp[2],x3=xp[3];
      float w0v=wp[(f<<5)+g],w1v=wp[1024+(f<<5)+g],w2v=wp[2048+(f<<5)+g],w3v=wp[3072+(f<<5)+g];
      A[0]=fmaf(x0.x,w0v,A[0]);  A[1]=fmaf(x0.y,w1v,A[1]);  A[2]=fmaf(x0.z,w1v,A[2]);  A[3]=fmaf(x0.w,w1v,A[3]);
      A[4]=fmaf(x1.x,w2v,A[4]);  A[5]=fmaf(x1.y,w2v,A[5]);  A[6]=fmaf(x1.z,w2v,A[6]);  A[7]=fmaf(x1.w,w2v,A[7]);
      A[8]=fmaf(x2.x,w2v,A[8]);  A[9]=fmaf(x2.y,w3v,A[9]);  A[10]=fmaf(x2.z,w3v,A[10]);A[11]=fmaf(x2.w,w3v,A[11]);
      A[12]=fmaf(x3.x,w3v,A[12]);A[13]=fmaf(x3.y,w3v,A[13]);A[14]=fmaf(x3.z,w3v,A[14]);A[15]=fmaf(x3.w,w3v,A[15]);
    }
    float B2[16],B3[16];
    #pragma unroll
    for(int c=0;c<16;c++){ B2[c]=0.f; B3[c]=0.f; }
    tpn_paths<0>(A,A,B2);
    tpn_paths<0>(B2,A,B3);
    float wa=pb0[zz*96+g], wb=pb0[zz*96+32+g], wc=pb0[zz*96+64+g];
    #pragma unroll
    for(int c=0;c<16;c++) sh1[n0*512+g*16+c]=wa*A[c]+wb*B2[c]+wc*B3[c];
  }
  __syncthreads();
  // pblin0 mix (cross-f from sh1) -> feats -> sh2
  if(act){
    float ft[16];
    #pragma unroll
    for(int c=0;c<16;c++) ft[c]=0.f;
    const float* wp=pblin0;
    #pragma unroll 8
    for(int f=0;f<NF;f++){
      const float4* xp=(const float4*)(sh1+n0*512+f*16);
      float4 x0=xp[0],x1=xp[1],x2=xp[2],x3=xp[3];
      float w0v=wp[(f<<5)+g],w1v=wp[1024+(f<<5)+g],w2v=wp[2048+(f<<5)+g],w3v=wp[3072+(f<<5)+g];
      ft[0]=fmaf(x0.x,w0v,ft[0]);  ft[1]=fmaf(x0.y,w1v,ft[1]);  ft[2]=fmaf(x0.z,w1v,ft[2]);  ft[3]=fmaf(x0.w,w1v,ft[3]);
      ft[4]=fmaf(x1.x,w2v,ft[4]);  ft[5]=fmaf(x1.y,w2v,ft[5]);  ft[6]=fmaf(x1.z,w2v,ft[6]);  ft[7]=fmaf(x1.w,w2v,ft[7]);
      ft[8]=fmaf(x2.x,w2v,ft[8]);  ft[9]=fmaf(x2.y,w3v,ft[9]);  ft[10]=fmaf(x2.z,w3v,ft[10]);ft[11]=fmaf(x2.w,w3v,ft[11]);
      ft[12]=fmaf(x3.x,w3v,ft[12]);ft[13]=fmaf(x3.y,w3v,ft[13]);ft[14]=fmaf(x3.z,w3v,ft[14]);ft[15]=fmaf(x3.w,w3v,ft[15]);
    }
    #pragma unroll
    for(int c=0;c<16;c++) sh2[n0*512+g*16+c]=ft[c];
  }
  __syncthreads();
  if(act){
    // readout: resid + e0 from feats scalar channel
    const float* wp=res1+(size_t)zz*1024;
    float a=0.f;
    #pragma unroll 8
    for(int f=0;f<32;f++) a=fmaf(sh2[n0*512+f*16], wp[(f<<5)+g], a);
    resid[(size_t)n*32+g]=a;
    if(g==0){
      float b=0.f;
      #pragma unroll 8
      for(int f=0;f<32;f++) b=fmaf(sh2[n0*512+f*16], ro0[f], b);
      e0[n]=b;
    }
    // up1 mix -> bf16 hl16 (layer-1 hlin)
    float acc[16];
    #pragma unroll
    for(int c=0;c<16;c++) acc[c]=0.f;
    const float* wp2=up1;
    #pragma unroll 8
    for(int f=0;f<NF;f++){
      const float4* xp=(const float4*)(sh2+n0*512+f*16);
      float4 x0=xp[0],x1=xp[1],x2=xp[2],x3=xp[3];
      float w0v=wp2[(f<<5)+g],w1v=wp2[1024+(f<<5)+g],w2v=wp2[2048+(f<<5)+g],w3v=wp2[3072+(f<<5)+g];
      acc[0]=fmaf(x0.x,w0v,acc[0]);  acc[1]=fmaf(x0.y,w1v,acc[1]);  acc[2]=fmaf(x0.z,w1v,acc[2]);  acc[3]=fmaf(x0.w,w1v,acc[3]);
      acc[4]=fmaf(x1.x,w2v,acc[4]);  acc[5]=fmaf(x1.y,w2v,acc[5]);  acc[6]=fmaf(x1.z,w2v,acc[6]);  acc[7]=fmaf(x1.w,w2v,acc[7]);
      acc[8]=fmaf(x2.x,w2v,acc[8]);  acc[9]=fmaf(x2.y,w3v,acc[9]);  acc[10]=fmaf(x2.z,w3v,acc[10]);acc[11]=fmaf(x2.w,w3v,acc[11]);
      acc[12]=fmaf(x3.x,w3v,acc[12]);acc[13]=fmaf(x3.y,w3v,acc[13]);acc[14]=fmaf(x3.z,w3v,acc[14]);acc[15]=fmaf(x3.w,w3v,acc[15]);
    }
    bf16x8 o0,o1;
    #pragma unroll
    for(int c=0;c<8;c++){ o0[c]=(short)f2bf(acc[c]); o1[c]=(short)f2bf(acc[8+c]); }
    bf16x8* op=(bf16x8*)(hl16+(size_t)n*512+g*16);
    op[0]=o0; op[1]=o1;
  }
}

// ---------------- fused layer-1 node chain: lin(post1)+tp_node_sc(pb1)+pblin1+final ----------------
__global__ __launch_bounds__(256) void k_node1(
    const float* __restrict__ agg, const float* __restrict__ post1,
    const float* __restrict__ pb1, const float* __restrict__ pblin1,
    const int* __restrict__ z, const float* __restrict__ resid,
    const float* __restrict__ e0a, const float* __restrict__ ro1a,
    const float* __restrict__ ro1b, float* __restrict__ out, int N)
{
  __shared__ float sh[8*32];
  __shared__ float sh2[8*32];
  __shared__ float red[8];
  int tid=threadIdx.x;
  int n0=tid>>5, g=tid&31;
  int n=blockIdx.x*8+n0;
  bool act=(n<N);
  if(act){
    const float* wp=post1;
    const float* ip=agg+(size_t)n*512;
    float A[16];
    #pragma unroll
    for(int c=0;c<16;c++) A[c]=0.f;
    #pragma unroll 8
    for(int f=0;f<NF;f++){
      const float4* xp=(const float4*)(ip+f*16);
      float4 x0=xp[0],x1=xp[1],x2=xp[2],x3=xp[3];
      float w0v=wp[(f<<5)+g],w1v=wp[1024+(f<<5)+g],w2v=wp[2048+(f<<5)+g],w3v=wp[3072+(f<<5)+g];
      A[0]=fmaf(x0.x,w0v,A[0]);  A[1]=fmaf(x0.y,w1v,A[1]);  A[2]=fmaf(x0.z,w1v,A[2]);  A[3]=fmaf(x0.w,w1v,A[3]);
      A[4]=fmaf(x1.x,w2v,A[4]);  A[5]=fmaf(x1.y,w2v,A[5]);  A[6]=fmaf(x1.z,w2v,A[6]);  A[7]=fmaf(x1.w,w2v,A[7]);
      A[8]=fmaf(x2.x,w2v,A[8]);  A[9]=fmaf(x2.y,w3v,A[9]);  A[10]=fmaf(x2.z,w3v,A[10]);A[11]=fmaf(x2.w,w3v,A[11]);
      A[12]=fmaf(x3.x,w3v,A[12]);A[13]=fmaf(x3.y,w3v,A[13]);A[14]=fmaf(x3.z,w3v,A[14]);A[15]=fmaf(x3.w,w3v,A[15]);
    }
    float B2[16];
    #pragma unroll
    for(int c=0;c<16;c++) B2[c]=0.f;
    tpn_paths<0>(A,A,B2);
    float B3_0=tpn_scalar(B2,A);
    int zz=z[n];
    float wa=pb1[zz*96+g], wb=pb1[zz*96+32+g], wc=pb1[zz*96+64+g];
    sh[n0*32+g]=wa*A[0]+wb*B2[0]+wc*B3_0;
  }
  __syncthreads();
  if(act){
    float a=0.f;
    #pragma unroll 8
    for(int f=0;f<32;f++) a=fmaf(sh[n0*32+f], pblin1[(f<<5)+g], a);
    sh2[n0*32+g]=a+resid[(size_t)n*32+g];
  }
  __syncthreads();
  if(g==0){
    float val=0.f;
    if(act){
      float e1=0.f;
      #pragma unroll
      for(int j=0;j<16;j++){
        float a=0.f;
        #pragma unroll
        for(int f=0;f<32;f++) a=fmaf(sh2[n0*32+f],ro1a[f*16+j],a);
        float s=a/(1.f+__expf(-a));
        e1=fmaf(s,ro1b[j],e1);
      }
      val=-1.5f+2.0f*(e0a[n]+e1)-10.0f;
    }
    red[n0]=val;
  }
  __syncthreads();
  if(tid==0){
    float s=0.f;
    #pragma unroll
    for(int i=0;i<8;i++) s+=red[i];
    atomicAdd(out,s);
  }
}

// ---------------- host orchestration ----------------
extern "C" void kernel_launch(void* const* d_in, const int* in_sizes, int n_in,
                              void* d_out, int out_size, void* d_ws, size_t ws_size,
                              hipStream_t stream)
{
  const float* vec   =(const float*)d_in[0];
  const int*   zarr  =(const int*)  d_in[1];
  const int*   snd   =(const int*)  d_in[2];
  const int*   rcv   =(const int*)  d_in[3];
  const float* embed =(const float*)d_in[4];
  const float* r0w0  =(const float*)d_in[5];
  const float* r0w1  =(const float*)d_in[6];
  const float* r0w2  =(const float*)d_in[7];
  const float* up0   =(const float*)d_in[8];
  const float* post0 =(const float*)d_in[9];
  const float* pb0   =(const float*)d_in[10];
  const float* pblin0=(const float*)d_in[11];
  const float* r1w0  =(const float*)d_in[12];
  const float* r1w1  =(const float*)d_in[13];
  const float* r1w2  =(const float*)d_in[14];
  const float* up1   =(const float*)d_in[15];
  const float* post1 =(const float*)d_in[16];
  const float* pb1   =(const float*)d_in[17];
  const float* pblin1=(const float*)d_in[18];
  const float* sel0  =(const float*)d_in[19];
  const float* ro0   =(const float*)d_in[20];
  const float* res1  =(const float*)d_in[21];
  const float* ro1a  =(const float*)d_in[22];
  const float* ro1b  =(const float*)d_in[23];

  const int E = in_sizes[0]/3;
  const int N = in_sizes[1];
  const int Epad = (E+63)&~63;

  char* ws=(char*)d_ws;
  size_t o=0;
  auto alloc=[&](size_t bytes)->char*{
    char* p=ws+o;
    o=(o+bytes+255)&~(size_t)255;
    return p;
  };
  int*   deg  =(int*)  alloc((size_t)N*4);
  int*   rowp =(int*)  alloc((size_t)(N+1)*4);
  int*   cur  =(int*)  alloc((size_t)N*4);
  int*   eid  =(int*)  alloc((size_t)E*4);
  int*   snd_s=(int*)  alloc((size_t)E*4);
  float* Yb   =(float*)alloc((size_t)E*16*4);
  float* radb =(float*)alloc((size_t)E*8*4);
  unsigned short* hidb=(unsigned short*)alloc((size_t)(Epad+16)*64*2);
  unsigned short* w2t0=(unsigned short*)alloc((size_t)1088*64*2);
  unsigned short* w2t1=(unsigned short*)alloc((size_t)1088*64*2);
  unsigned short* hl16=(unsigned short*)alloc((size_t)N*512*2);
  float* combw=(float*)alloc((size_t)10*4096*4);
  float* bufB =(float*)alloc((size_t)N*512*4);
  float* bufC =(float*)alloc((size_t)N*512*4);
  float* e0b  =(float*)alloc((size_t)N*4);
  float* residb=(float*)alloc((size_t)N*32*4);
  char*  dyn  = ws+o;
  size_t remain = ws_size>o ? ws_size-o : 0;

  dim3 tb(256);
  dim3 nblk((unsigned)((N*32+255)/256));
  dim3 n8blk((unsigned)((N+7)/8));
  dim3 eblk((unsigned)((E+255)/256));
  dim3 qblk((unsigned)((N*64+255)/256));

  // CSR build (receiver-sorted edge order)
  hipMemsetAsync(deg,0,(size_t)N*4,stream);
  k_count<<<eblk,tb,0,stream>>>(rcv,deg,E);
  k_scan<<<dim3(1),dim3(1024),0,stream>>>(deg,rowp,cur,N);
  k_fill<<<eblk,tb,0,stream>>>(rcv,cur,eid,E);

  k_edge_setup<<<eblk,tb,0,stream>>>(vec,snd,eid,Yb,radb,snd_s,E);
  k_prep<<<dim3((2*1088*64+10*4096+255)/256),tb,0,stream>>>(r0w2,r1w2,w2t0,w2t1,post0,sel0,combw);
  k_embed16<<<nblk,tb,0,stream>>>(embed,up0,zarr,hl16,N);

  auto run_edges=[&](bool l0, const unsigned short* hlin, const unsigned short* w2t, float* agg){
    long rows = (long)(remain/1024);
    rows -= rows%64;
    if (rows>(long)Epad) rows=Epad;
    if (rows<64) rows=64;
    unsigned short* msgsb = (unsigned short*)dyn;
    for(long eb=0;eb<E;eb+=rows){
      long cnt = E-eb; if(cnt>rows) cnt=rows;
      dim3 g2((unsigned)((cnt+15)/16));
      if(l0) k_tp_fused<true ><<<g2,tb,0,stream>>>(hlin,Yb,hidb+(size_t)eb*64,w2t,snd_s,msgsb,(int)eb,(int)cnt);
      else   k_tp_fused<false><<<g2,tb,0,stream>>>(hlin,Yb,hidb+(size_t)eb*64,w2t,snd_s,msgsb,(int)eb,(int)cnt);
      if(eb==0) k_seg_sum<true ><<<qblk,tb,0,stream>>>(msgsb,rowp,agg,(int)eb,(int)cnt,N);
      else      k_seg_sum<false><<<qblk,tb,0,stream>>>(msgsb,rowp,agg,(int)eb,(int)cnt,N);
    }
  };

  // ---- layer 0 ----
  k_radial<<<eblk,tb,0,stream>>>(radb,r0w0,r0w1,hidb,E);
  run_edges(true,hl16,w2t0,bufB);
  k_node0<<<n8blk,tb,0,stream>>>(bufB,combw,pb0,pblin0,ro0,res1,up1,zarr,e0b,residb,hl16,N);

  // ---- layer 1 ----
  k_radial<<<eblk,tb,0,stream>>>(radb,r1w0,r1w1,hidb,E);
  run_edges(false,hl16,w2t1,bufC);
  hipMemsetAsync(d_out,0,4,stream);
  k_node1<<<n8blk,tb,0,stream>>>(bufC,post1,pb1,pblin1,zarr,residb,e0b,ro1a,ro1b,(float*)d_out,N);
}